// Round 1
// baseline (1445.446 us; speedup 1.0000x reference)
//
#include <hip/hip_runtime.h>
#include <cstdio>
#include <math.h>

// ---------------------------------------------------------------------------
// MeshEncoderDecoder — round 1: correctness-first f32 implementation.
//
// Internal layout: edge-major [b][E][C] so mesh-conv neighbor gathers read
// contiguous C-vectors. x2_e / x2_p live directly in d_out (channel-major,
// written by a transposing norm kernel). All convs are LDS-tiled GEMMs:
// 64-edge tile x O outputs, K staged in chunks. inorm stats are fused as
// deterministic per-block partials (no float atomics).
// ---------------------------------------------------------------------------

#define E_TOT 50000
#define B_TOT 2
#define TILE_E 64
#define NBLK ((E_TOT + TILE_E - 1) / TILE_E)   // 782

__device__ __forceinline__ float sigmoidf_(float x) {
    return 1.0f / (1.0f + __expf(-x));
}

// ---------------------------------------------------------------------------
// transpose fe (b, 8, E) -> fe_t (b, E, 8)
// ---------------------------------------------------------------------------
__global__ __launch_bounds__(256)
void transpose_in_k(const float* __restrict__ fe, float* __restrict__ fet)
{
    int b = blockIdx.z;
    int e = blockIdx.x * 256 + threadIdx.x;
    if (e >= E_TOT) return;
    float v[8];
#pragma unroll
    for (int c = 0; c < 8; ++c)
        v[c] = fe[((long)b * 8 + c) * E_TOT + e];
    float4* dst = (float4*)&fet[((long)b * E_TOT + e) * 8];
    dst[0] = make_float4(v[0], v[1], v[2], v[3]);
    dst[1] = make_float4(v[4], v[5], v[6], v[7]);
}

// ---------------------------------------------------------------------------
// mesh_conv: y[b,e,o] = sum_{c,s} w[o,c,s] * G[b,e,c,s]  (+bias)
// G[...,0]=x, 1=f1+f3, 2=f2+f4, 3=|f1-f3|, 4=|f2-f4|  (fk = x at gemm[b,e,k-1])
// Input edge-major: x[b*bstr + e*inC + c0 + c]. Output edge-major,
// stride outS, column offset oOff. Optional per-block stats partials.
// ---------------------------------------------------------------------------
template<int C, int O, bool STATS>
__global__ __launch_bounds__(256)
void mesh_conv_k(const float* __restrict__ x, long bstr, int inC, int c0,
                 const int* __restrict__ gemm,
                 const float* __restrict__ w, const float* __restrict__ bias,
                 float* __restrict__ y, long ybstr, int outS, int oOff,
                 float* __restrict__ part)
{
    constexpr int CC = (C >= 16) ? 16 : C;
    constexpr int K  = CC * 5;
    constexpr int NCHUNK = C / CC;
    constexpr int OG = O / 4;          // threads along o (each owns 4 outputs)
    constexpr int EG = 256 / OG;       // thread groups along e
    constexpr int ET = TILE_E / EG;    // edges per thread

    __shared__ float Wl[K][O];
    __shared__ float Gl[K][TILE_E];
    __shared__ int   nidx[TILE_E][4];
    __shared__ float red[STATS ? (2 * O * (EG + 1)) : 4];

    const int tid = threadIdx.x;
    const int b  = blockIdx.z;
    const int e0 = blockIdx.x * TILE_E;

    { // stage neighbor indices (64 edges x 4)
        int e = tid >> 2, s = tid & 3;
        int eg = e0 + e;
        nidx[e][s] = (eg < E_TOT) ? gemm[((long)b * E_TOT + eg) * 4 + s] : 0;
    }
    __syncthreads();

    const int od  = (tid % OG) * 4;
    const int teB = (tid / OG) * ET;

    float acc[ET][4];
#pragma unroll
    for (int i = 0; i < ET; ++i)
#pragma unroll
        for (int j = 0; j < 4; ++j) acc[i][j] = 0.f;

    const float* xb = x + (long)b * bstr;

    for (int ch = 0; ch < NCHUNK; ++ch) {
        const int cb = ch * CC;
        // ---- stage W chunk: Wl[k][o] = w[o*C*5 + cb*5 + k]
        if constexpr ((K % 4) == 0) {
            constexpr int KQ = K / 4;
            for (int q = tid; q < O * KQ; q += 256) {
                int o = q / KQ, kq = q % KQ;
                float4 wv = *(const float4*)&w[(long)o * C * 5 + cb * 5 + kq * 4];
                const float* wp = &wv.x;
#pragma unroll
                for (int j = 0; j < 4; ++j) Wl[kq * 4 + j][o] = wp[j];
            }
        } else {
            for (int q = tid; q < O * K; q += 256) {
                int o = q / K, k = q % K;
                Wl[k][o] = w[(long)o * C * 5 + cb * 5 + k];
            }
        }
        // ---- stage G chunk
        if constexpr ((CC % 4) == 0) {
            constexpr int CQ = CC / 4;
            for (int q = tid; q < TILE_E * CQ; q += 256) {
                int e = q / CQ, cq = q % CQ;
                int eg = e0 + e;
                int se = (eg < E_TOT) ? eg : 0;
                long cofs = (long)(c0 + cb + cq * 4);
                float4 s0 = *(const float4*)&xb[(long)se * inC + cofs];
                int4 nn = *(const int4*)&nidx[e][0];
                float4 f1 = *(const float4*)&xb[(long)nn.x * inC + cofs];
                float4 f2 = *(const float4*)&xb[(long)nn.y * inC + cofs];
                float4 f3 = *(const float4*)&xb[(long)nn.z * inC + cofs];
                float4 f4 = *(const float4*)&xb[(long)nn.w * inC + cofs];
                const float *p0 = &s0.x, *p1 = &f1.x, *p2 = &f2.x, *p3 = &f3.x, *p4 = &f4.x;
#pragma unroll
                for (int j = 0; j < 4; ++j) {
                    int kb = (cq * 4 + j) * 5;
                    float v1 = p1[j], v2 = p2[j], v3 = p3[j], v4 = p4[j];
                    Gl[kb + 0][e] = p0[j];
                    Gl[kb + 1][e] = v1 + v3;
                    Gl[kb + 2][e] = v2 + v4;
                    Gl[kb + 3][e] = fabsf(v1 - v3);
                    Gl[kb + 4][e] = fabsf(v2 - v4);
                }
            }
        } else {
            for (int q = tid; q < TILE_E * CC; q += 256) {
                int e = q / CC, c = q % CC;
                int eg = e0 + e;
                int se = (eg < E_TOT) ? eg : 0;
                long cofs = (long)(c0 + cb + c);
                float s0 = xb[(long)se * inC + cofs];
                int4 nn = *(const int4*)&nidx[e][0];
                float v1 = xb[(long)nn.x * inC + cofs];
                float v2 = xb[(long)nn.y * inC + cofs];
                float v3 = xb[(long)nn.z * inC + cofs];
                float v4 = xb[(long)nn.w * inC + cofs];
                int kb = c * 5;
                Gl[kb + 0][e] = s0;
                Gl[kb + 1][e] = v1 + v3;
                Gl[kb + 2][e] = v2 + v4;
                Gl[kb + 3][e] = fabsf(v1 - v3);
                Gl[kb + 4][e] = fabsf(v2 - v4);
            }
        }
        __syncthreads();
        // ---- compute
#pragma unroll 4
        for (int k = 0; k < K; ++k) {
            float4 wv = *(const float4*)&Wl[k][od];
            float g[ET];
            if constexpr (ET >= 4) {
#pragma unroll
                for (int i = 0; i < ET; i += 4) {
                    float4 gv = *(const float4*)&Gl[k][teB + i];
                    g[i] = gv.x; g[i + 1] = gv.y; g[i + 2] = gv.z; g[i + 3] = gv.w;
                }
            } else {
                float2 gv = *(const float2*)&Gl[k][teB];
                g[0] = gv.x; g[1] = gv.y;
            }
#pragma unroll
            for (int i = 0; i < ET; ++i) {
                acc[i][0] = fmaf(g[i], wv.x, acc[i][0]);
                acc[i][1] = fmaf(g[i], wv.y, acc[i][1]);
                acc[i][2] = fmaf(g[i], wv.z, acc[i][2]);
                acc[i][3] = fmaf(g[i], wv.w, acc[i][3]);
            }
        }
        __syncthreads();
    }

    if (bias) {
        float bv[4] = {bias[od], bias[od + 1], bias[od + 2], bias[od + 3]};
#pragma unroll
        for (int i = 0; i < ET; ++i)
#pragma unroll
            for (int j = 0; j < 4; ++j) acc[i][j] += bv[j];
    }

    float* yb = y + (long)b * ybstr;
#pragma unroll
    for (int i = 0; i < ET; ++i) {
        int eg = e0 + teB + i;
        if (eg < E_TOT) {
            float4 v = make_float4(acc[i][0], acc[i][1], acc[i][2], acc[i][3]);
            *(float4*)&yb[(long)eg * outS + oOff + od] = v;
        }
    }

    if constexpr (STATS) {
        const int tg = tid / OG;   // 0..EG-1
        float* red1 = red;
        float* red2 = red + O * (EG + 1);
#pragma unroll
        for (int j = 0; j < 4; ++j) {
            float s1 = 0.f, s2 = 0.f;
#pragma unroll
            for (int i = 0; i < ET; ++i) {
                int eg = e0 + teB + i;
                if (eg < E_TOT) { float v = acc[i][j]; s1 += v; s2 += v * v; }
            }
            red1[(od + j) * (EG + 1) + tg] = s1;
            red2[(od + j) * (EG + 1) + tg] = s2;
        }
        __syncthreads();
        if (tid < O) {
            float s = 0.f;
            for (int t = 0; t < EG; ++t) s += red1[tid * (EG + 1) + t];
            part[(((long)b * NBLK + blockIdx.x) * O + tid) * 2 + 0] = s;
        } else if (tid < 2 * O) {
            int o = tid - O;
            float s = 0.f;
            for (int t = 0; t < EG; ++t) s += red2[o * (EG + 1) + t];
            part[(((long)b * NBLK + blockIdx.x) * O + o) * 2 + 1] = s;
        }
    }
}

// ---------------------------------------------------------------------------
// 1x1 conv: y[b,e,o] = sum_c w[o,c] * x[b,e,c] + bias
// Generic input addressing: x[b*bstr + e*estr + (c0+c)*cstr]
//   edge-major: estr=inC, cstr=1 ; channel-major: estr=1, cstr=E
// ---------------------------------------------------------------------------
template<int C, int O, bool STATS>
__global__ __launch_bounds__(256)
void conv1_k(const float* __restrict__ x, long bstr, long estr, long cstr, int c0,
             const float* __restrict__ w, const float* __restrict__ bias,
             float* __restrict__ y, long ybstr, int outS, int oOff,
             float* __restrict__ part)
{
    constexpr int CC = (C >= 32) ? 32 : C;
    constexpr int NCHUNK = C / CC;
    constexpr int OG = O / 4;
    constexpr int EG = 256 / OG;
    constexpr int ET = TILE_E / EG;

    __shared__ float Wl[CC][O];
    __shared__ float Gl[CC][TILE_E];
    __shared__ float red[STATS ? (2 * O * (EG + 1)) : 4];

    const int tid = threadIdx.x;
    const int b  = blockIdx.z;
    const int e0 = blockIdx.x * TILE_E;

    const int od  = (tid % OG) * 4;
    const int teB = (tid / OG) * ET;

    float acc[ET][4];
#pragma unroll
    for (int i = 0; i < ET; ++i)
#pragma unroll
        for (int j = 0; j < 4; ++j) acc[i][j] = 0.f;

    const float* xb = x + (long)b * bstr;

    for (int ch = 0; ch < NCHUNK; ++ch) {
        const int cb = ch * CC;
        // ---- stage W: Wl[k][o] = w[o*C + cb + k]
        {
            constexpr int KQ = CC / 4;
            for (int q = tid; q < O * KQ; q += 256) {
                int o = q / KQ, kq = q % KQ;
                float4 wv = *(const float4*)&w[(long)o * C + cb + kq * 4];
                const float* wp = &wv.x;
#pragma unroll
                for (int j = 0; j < 4; ++j) Wl[kq * 4 + j][o] = wp[j];
            }
        }
        // ---- stage G
        if (cstr == 1) {
            // edge-major: vectorize over c
            constexpr int CQ = CC / 4;
            for (int q = tid; q < TILE_E * CQ; q += 256) {
                int e = q / CQ, cq = q % CQ;
                int eg = e0 + e;
                int se = (eg < E_TOT) ? eg : 0;
                float4 v = *(const float4*)&xb[(long)se * estr + (c0 + cb + cq * 4)];
                const float* vp = &v.x;
#pragma unroll
                for (int j = 0; j < 4; ++j) Gl[cq * 4 + j][e] = vp[j];
            }
        } else {
            // channel-major (estr==1): vectorize over e
            for (int q = tid; q < CC * (TILE_E / 4); q += 256) {
                int c = q / (TILE_E / 4), eq = q % (TILE_E / 4);
                int e4 = e0 + eq * 4;
                float4 v;
                if (e4 + 3 < E_TOT) {
                    v = *(const float4*)&x[(long)b * bstr + (long)(c0 + cb + c) * cstr + e4];
                } else {
                    float* vp = &v.x;
#pragma unroll
                    for (int j = 0; j < 4; ++j) {
                        int ej = e4 + j;
                        vp[j] = (ej < E_TOT)
                              ? x[(long)b * bstr + (long)(c0 + cb + c) * cstr + ej] : 0.f;
                    }
                }
                *(float4*)&Gl[c][eq * 4] = v;
            }
        }
        __syncthreads();
        // ---- compute
#pragma unroll 4
        for (int k = 0; k < CC; ++k) {
            float4 wv = *(const float4*)&Wl[k][od];
            float g[ET];
            if constexpr (ET >= 4) {
#pragma unroll
                for (int i = 0; i < ET; i += 4) {
                    float4 gv = *(const float4*)&Gl[k][teB + i];
                    g[i] = gv.x; g[i + 1] = gv.y; g[i + 2] = gv.z; g[i + 3] = gv.w;
                }
            } else {
                float2 gv = *(const float2*)&Gl[k][teB];
                g[0] = gv.x; g[1] = gv.y;
            }
#pragma unroll
            for (int i = 0; i < ET; ++i) {
                acc[i][0] = fmaf(g[i], wv.x, acc[i][0]);
                acc[i][1] = fmaf(g[i], wv.y, acc[i][1]);
                acc[i][2] = fmaf(g[i], wv.z, acc[i][2]);
                acc[i][3] = fmaf(g[i], wv.w, acc[i][3]);
            }
        }
        __syncthreads();
    }

    if (bias) {
        float bv[4] = {bias[od], bias[od + 1], bias[od + 2], bias[od + 3]};
#pragma unroll
        for (int i = 0; i < ET; ++i)
#pragma unroll
            for (int j = 0; j < 4; ++j) acc[i][j] += bv[j];
    }

    float* yb = y + (long)b * ybstr;
#pragma unroll
    for (int i = 0; i < ET; ++i) {
        int eg = e0 + teB + i;
        if (eg < E_TOT) {
            float4 v = make_float4(acc[i][0], acc[i][1], acc[i][2], acc[i][3]);
            *(float4*)&yb[(long)eg * outS + oOff + od] = v;
        }
    }

    if constexpr (STATS) {
        const int tg = tid / OG;
        float* red1 = red;
        float* red2 = red + O * (EG + 1);
#pragma unroll
        for (int j = 0; j < 4; ++j) {
            float s1 = 0.f, s2 = 0.f;
#pragma unroll
            for (int i = 0; i < ET; ++i) {
                int eg = e0 + teB + i;
                if (eg < E_TOT) { float v = acc[i][j]; s1 += v; s2 += v * v; }
            }
            red1[(od + j) * (EG + 1) + tg] = s1;
            red2[(od + j) * (EG + 1) + tg] = s2;
        }
        __syncthreads();
        if (tid < O) {
            float s = 0.f;
            for (int t = 0; t < EG; ++t) s += red1[tid * (EG + 1) + t];
            part[(((long)b * NBLK + blockIdx.x) * O + tid) * 2 + 0] = s;
        } else if (tid < 2 * O) {
            int o = tid - O;
            float s = 0.f;
            for (int t = 0; t < EG; ++t) s += red2[o * (EG + 1) + t];
            part[(((long)b * NBLK + blockIdx.x) * O + o) * 2 + 1] = s;
        }
    }
}

// ---------------------------------------------------------------------------
// finalize inorm stats: partials [b][NBLK][128][2] -> stats [b][128][2]=(mean,rstd)
// ---------------------------------------------------------------------------
__global__ void stats_fin_k(const float* __restrict__ part, float* __restrict__ stats)
{
    int t = threadIdx.x;          // 256 = B*128
    int b = t >> 7, o = t & 127;
    float s1 = 0.f, s2 = 0.f;
    for (int k = 0; k < NBLK; ++k) {
        long base = (((long)b * NBLK + k) * 128 + o) * 2;
        s1 += part[base];
        s2 += part[base + 1];
    }
    float mean = s1 / (float)E_TOT;
    float var  = s2 / (float)E_TOT - mean * mean;
    var = fmaxf(var, 0.f);
    stats[(b * 128 + o) * 2 + 0] = mean;
    stats[(b * 128 + o) * 2 + 1] = rsqrtf(var + 1e-5f);
}

// ---------------------------------------------------------------------------
// elementwise norm+activation, edge-major in/out (C=128). ACT 0=relu 1=sigmoid
// ---------------------------------------------------------------------------
template<int ACT>
__global__ __launch_bounds__(256)
void norm_act_em_k(const float* __restrict__ xin, const float* __restrict__ stats,
                   float* __restrict__ yout)
{
    long q = (long)blockIdx.x * 256 + threadIdx.x;
    long tot = (long)B_TOT * E_TOT * 128 / 4;
    if (q >= tot) return;
    long idx = q * 4;
    int c = (int)(idx & 127);
    long be = idx >> 7;
    int b = (int)(be / E_TOT);
    float4 v = *(const float4*)&xin[idx];
    float* vp = &v.x;
#pragma unroll
    for (int j = 0; j < 4; ++j) {
        float2 st = *(const float2*)&stats[(b * 128 + c + j) * 2];
        float t = (vp[j] - st.x) * st.y;
        vp[j] = (ACT == 0) ? fmaxf(t, 0.f) : sigmoidf_(t);
    }
    *(float4*)&yout[idx] = v;
}

// ---------------------------------------------------------------------------
// x2 = relu(inorm(tmp) + res), written channel-major into d_out section `sect`
// ---------------------------------------------------------------------------
__global__ __launch_bounds__(256)
void norm_res_cm_k(const float* __restrict__ xin, const float* __restrict__ res,
                   const float* __restrict__ stats, float* __restrict__ outb, int sect)
{
    __shared__ float T[32 * 68];
    int b = blockIdx.z, cg = blockIdx.y;
    int e0 = blockIdx.x * 64;
    int tid = threadIdx.x;
#pragma unroll
    for (int i = 0; i < 2; ++i) {
        int q = tid + i * 256;
        int e = q >> 3, cq = q & 7;
        int eg = e0 + e;
        int se = (eg < E_TOT) ? eg : (E_TOT - 1);
        int c = cg * 32 + cq * 4;
        long base = ((long)b * E_TOT + se) * 128 + c;
        float4 v = *(const float4*)&xin[base];
        float4 r = *(const float4*)&res[base];
        float* vp = &v.x; float* rp = &r.x;
#pragma unroll
        for (int j = 0; j < 4; ++j) {
            float2 st = *(const float2*)&stats[(b * 128 + c + j) * 2];
            float t = (vp[j] - st.x) * st.y + rp[j];
            T[(cq * 4 + j) * 68 + e] = fmaxf(t, 0.f);
        }
    }
    __syncthreads();
#pragma unroll
    for (int i = 0; i < 2; ++i) {
        int q = tid + i * 256;
        int cl = q >> 4, eq = q & 15;
        int e4 = e0 + eq * 4;
        int cglob = sect + cg * 32 + cl;
        float4 v = *(const float4*)&T[cl * 68 + eq * 4];
        long obase = ((long)b * 384 + cglob) * E_TOT + e4;
        if (e4 + 3 < E_TOT) {
            *(float4*)&outb[obase] = v;
        } else {
            const float* vp = &v.x;
            for (int j = 0; j < 4; ++j)
                if (e4 + j < E_TOT) outb[obase + j] = vp[j];
        }
    }
}

// ---------------------------------------------------------------------------
// final: s = sigmoid(wA - wB); agg = x2e*s + x2p*(1-s); write channel-major
// ---------------------------------------------------------------------------
__global__ __launch_bounds__(256)
void final_agg_k(const float* __restrict__ wA, const float* __restrict__ wB,
                 float* __restrict__ outb)
{
    __shared__ float S[32 * 68];
    int b = blockIdx.z, cg = blockIdx.y;
    int e0 = blockIdx.x * 64;
    int tid = threadIdx.x;
#pragma unroll
    for (int i = 0; i < 2; ++i) {
        int q = tid + i * 256;
        int e = q >> 3, cq = q & 7;
        int eg = e0 + e;
        int se = (eg < E_TOT) ? eg : (E_TOT - 1);
        int c = cg * 32 + cq * 4;
        long base = ((long)b * E_TOT + se) * 128 + c;
        float4 a = *(const float4*)&wA[base];
        float4 bb = *(const float4*)&wB[base];
        const float* ap = &a.x; const float* bp = &bb.x;
#pragma unroll
        for (int j = 0; j < 4; ++j)
            S[(cq * 4 + j) * 68 + e] = sigmoidf_(ap[j] - bp[j]);
    }
    __syncthreads();
#pragma unroll
    for (int i = 0; i < 2; ++i) {
        int q = tid + i * 256;
        int cl = q >> 4, eq = q & 15;
        int e4 = e0 + eq * 4;
        int cglob = cg * 32 + cl;
        float4 s = *(const float4*)&S[cl * 68 + eq * 4];
        long eb = ((long)b * 384 + cglob) * E_TOT + e4;
        long pb = ((long)b * 384 + 128 + cglob) * E_TOT + e4;
        long ab = ((long)b * 384 + 256 + cglob) * E_TOT + e4;
        if (e4 + 3 < E_TOT) {
            float4 xe = *(const float4*)&outb[eb];
            float4 xp = *(const float4*)&outb[pb];
            float* sp = &s.x; float* xep = &xe.x; float* xpp = &xp.x;
            float4 r;
            float* rp = &r.x;
#pragma unroll
            for (int j = 0; j < 4; ++j)
                rp[j] = xep[j] * sp[j] + xpp[j] * (1.f - sp[j]);
            *(float4*)&outb[ab] = r;
        } else {
            const float* sp = &s.x;
            for (int j = 0; j < 4; ++j) {
                if (e4 + j < E_TOT) {
                    float xe = outb[eb + j], xp = outb[pb + j];
                    outb[ab + j] = xe * sp[j] + xp * (1.f - sp[j]);
                }
            }
        }
    }
}

// ---------------------------------------------------------------------------
extern "C" void kernel_launch(void* const* d_in, const int* in_sizes, int n_in,
                              void* d_out, int out_size, void* d_ws, size_t ws_size,
                              hipStream_t stream)
{
    const float* fe   = (const float*)d_in[0];
    const int*   gemm = (const int*)  d_in[1];
    const float* w_e1 = (const float*)d_in[2];  const float* b_e1 = (const float*)d_in[3];
    const float* w_p1 = (const float*)d_in[4];  const float* b_p1 = (const float*)d_in[5];
    const float* w_e2 = (const float*)d_in[6];  const float* b_e2 = (const float*)d_in[7];
    const float* w_p2 = (const float*)d_in[8];  const float* b_p2 = (const float*)d_in[9];
    const float* wa   = (const float*)d_in[10]; const float* ba   = (const float*)d_in[11];
    const float* wb   = (const float*)d_in[12]; const float* bb   = (const float*)d_in[13];
    const float* wal  = (const float*)d_in[14]; const float* bal  = (const float*)d_in[15];
    const float* wbl  = (const float*)d_in[16]; const float* bbl  = (const float*)d_in[17];
    const float* wat  = (const float*)d_in[18]; const float* bat  = (const float*)d_in[19];
    const float* wbt  = (const float*)d_in[20]; const float* bbt  = (const float*)d_in[21];
    const float* waf  = (const float*)d_in[22]; const float* baf  = (const float*)d_in[23];
    const float* wbf  = (const float*)d_in[24]; const float* bbf  = (const float*)d_in[25];
    float* out = (float*)d_out;

    const long EB = (long)E_TOT;
    // workspace layout (floats)
    float* FET = (float*)d_ws;                       // B*E*8
    float* X1  = FET + (long)B_TOT * EB * 8;         // B*E*128 (x1_e / x1_p / x_all)
    float* TMP = X1  + (long)B_TOT * EB * 128;       // B*E*128 (pre-norm conv out)
    float* XA2 = TMP + (long)B_TOT * EB * 128;       // B*E*128 (x_a_two, then wA)
    float* XB2 = XA2 + (long)B_TOT * EB * 128;       // B*E*128 (x_b_two, then wB)
    float* PART  = XB2 + (long)B_TOT * EB * 128;     // B*NBLK*128*2
    float* STATS = PART + (long)B_TOT * NBLK * 128 * 2;

    const size_t ws_need = (size_t)((STATS + B_TOT * 128 * 2) - FET) * sizeof(float);
    if (ws_size < ws_need) {
        fprintf(stderr, "kernel_launch: ws too small (%zu < %zu)\n", ws_size, ws_need);
        return;
    }

    dim3 blk(256);
    dim3 gE(NBLK, 1, B_TOT);
    dim3 gT((E_TOT + 255) / 256, 1, B_TOT);
    dim3 gN(NBLK, 4, B_TOT);
    long nq = (long)B_TOT * E_TOT * 128 / 4;
    int gEW = (int)((nq + 255) / 256);

    transpose_in_k<<<gT, blk, 0, stream>>>(fe, FET);

    // ---- edge branch
    mesh_conv_k<5, 128, true><<<gE, blk, 0, stream>>>(FET, EB * 8, 8, 0, gemm,
        w_e1, b_e1, TMP, EB * 128, 128, 0, PART);
    stats_fin_k<<<1, 256, 0, stream>>>(PART, STATS);
    norm_act_em_k<0><<<gEW, blk, 0, stream>>>(TMP, STATS, X1);          // x1_e
    mesh_conv_k<128, 128, true><<<gE, blk, 0, stream>>>(X1, EB * 128, 128, 0, gemm,
        w_e2, b_e2, TMP, EB * 128, 128, 0, PART);
    stats_fin_k<<<1, 256, 0, stream>>>(PART, STATS);
    norm_res_cm_k<<<gN, blk, 0, stream>>>(TMP, X1, STATS, out, 0);      // x2_e -> out[:,0:128]

    // ---- point branch
    mesh_conv_k<3, 128, true><<<gE, blk, 0, stream>>>(FET, EB * 8, 8, 5, gemm,
        w_p1, b_p1, TMP, EB * 128, 128, 0, PART);
    stats_fin_k<<<1, 256, 0, stream>>>(PART, STATS);
    norm_act_em_k<0><<<gEW, blk, 0, stream>>>(TMP, STATS, X1);          // x1_p
    mesh_conv_k<128, 128, true><<<gE, blk, 0, stream>>>(X1, EB * 128, 128, 0, gemm,
        w_p2, b_p2, TMP, EB * 128, 128, 0, PART);
    stats_fin_k<<<1, 256, 0, stream>>>(PART, STATS);
    norm_res_cm_k<<<gN, blk, 0, stream>>>(TMP, X1, STATS, out, 128);    // x2_p -> out[:,128:256]

    // ---- x_all = concat(conv1(x2e,wa), conv1(x2p,wb))  (reads out channel-major)
    conv1_k<128, 32, false><<<gE, blk, 0, stream>>>(out, (long)384 * E_TOT, 1, EB, 0,
        wa, ba, X1, EB * 64, 64, 0, nullptr);
    conv1_k<128, 32, false><<<gE, blk, 0, stream>>>(out, (long)384 * E_TOT, 1, EB, 128,
        wb, bb, X1, EB * 64, 64, 32, nullptr);

    // ---- two-branch heads
    conv1_k<64, 64, false><<<gE, blk, 0, stream>>>(X1, EB * 64, 64, 1, 0,
        wal, bal, XA2, EB * 128, 128, 0, nullptr);
    mesh_conv_k<64, 64, false><<<gE, blk, 0, stream>>>(X1, EB * 64, 64, 0, gemm,
        wat, bat, XA2, EB * 128, 128, 64, nullptr);
    conv1_k<64, 64, false><<<gE, blk, 0, stream>>>(X1, EB * 64, 64, 1, 0,
        wbl, bbl, XB2, EB * 128, 128, 0, nullptr);
    mesh_conv_k<64, 64, false><<<gE, blk, 0, stream>>>(X1, EB * 64, 64, 0, gemm,
        wbt, bbt, XB2, EB * 128, 128, 64, nullptr);

    // ---- gates
    conv1_k<128, 128, true><<<gE, blk, 0, stream>>>(XA2, EB * 128, 128, 1, 0,
        waf, baf, TMP, EB * 128, 128, 0, PART);
    stats_fin_k<<<1, 256, 0, stream>>>(PART, STATS);
    norm_act_em_k<1><<<gEW, blk, 0, stream>>>(TMP, STATS, XA2);         // wA
    conv1_k<128, 128, true><<<gE, blk, 0, stream>>>(XB2, EB * 128, 128, 1, 0,
        wbf, bbf, TMP, EB * 128, 128, 0, PART);
    stats_fin_k<<<1, 256, 0, stream>>>(PART, STATS);
    norm_act_em_k<1><<<gEW, blk, 0, stream>>>(TMP, STATS, XB2);         // wB

    // ---- aggregate + write agg section
    final_agg_k<<<gN, blk, 0, stream>>>(XA2, XB2, out);
}

// Round 2
// 903.720 us; speedup vs baseline: 1.5994x; 1.5994x over previous
//
#include <hip/hip_runtime.h>
#include <cstdio>
#include <math.h>

// ---------------------------------------------------------------------------
// MeshEncoderDecoder — round 2: bf16-MFMA for the two C=128 mesh convs.
// Everything else unchanged from round 1.
// ---------------------------------------------------------------------------

#define E_TOT 50000
#define B_TOT 2
#define TILE_E 64
#define NBLK ((E_TOT + TILE_E - 1) / TILE_E)   // 782

typedef __attribute__((ext_vector_type(8))) short bf16x8;
typedef __attribute__((ext_vector_type(4))) float f32x4;

__device__ __forceinline__ float sigmoidf_(float x) {
    return 1.0f / (1.0f + __expf(-x));
}

__device__ __forceinline__ unsigned short f2bf(float f) {
    unsigned int u = __float_as_uint(f);
    unsigned int r = (u + 0x7fffu + ((u >> 16) & 1u)) >> 16;
    return (unsigned short)r;
}

// ---------------------------------------------------------------------------
// transpose fe (b, 8, E) -> fe_t (b, E, 8)
// ---------------------------------------------------------------------------
__global__ __launch_bounds__(256)
void transpose_in_k(const float* __restrict__ fe, float* __restrict__ fet)
{
    int b = blockIdx.z;
    int e = blockIdx.x * 256 + threadIdx.x;
    if (e >= E_TOT) return;
    float v[8];
#pragma unroll
    for (int c = 0; c < 8; ++c)
        v[c] = fe[((long)b * 8 + c) * E_TOT + e];
    float4* dst = (float4*)&fet[((long)b * E_TOT + e) * 8];
    dst[0] = make_float4(v[0], v[1], v[2], v[3]);
    dst[1] = make_float4(v[4], v[5], v[6], v[7]);
}

// ---------------------------------------------------------------------------
// weight transform for MFMA mesh conv: w [128][128][5] f32 -> wt [128][5][128] bf16
// (k-order becomes s-major: k = s*128 + c)
// ---------------------------------------------------------------------------
__global__ __launch_bounds__(256)
void wtrans_k(const float* __restrict__ w, unsigned short* __restrict__ wt)
{
    int idx = blockIdx.x * 256 + threadIdx.x;
    if (idx >= 128 * 640) return;
    int o = idx / 640, t = idx % 640;
    int s = t >> 7, c = t & 127;
    wt[idx] = f2bf(w[o * 640 + c * 5 + s]);
}

// ---------------------------------------------------------------------------
// MFMA mesh conv, C=128 -> O=128. x,y edge-major [b][E][128].
// wt: bf16 [128][5][128]. Emits inorm partials like mesh_conv_k<...,true>.
// Block: 64 edges x 128 outs, 256 threads (4 waves, each 64e x 32o).
// ---------------------------------------------------------------------------
__global__ __launch_bounds__(256)
void mesh_conv_mfma_k(const float* __restrict__ x, const int* __restrict__ gemm,
                      const unsigned short* __restrict__ wt,
                      const float* __restrict__ bias,
                      float* __restrict__ y, float* __restrict__ part)
{
    __shared__ bf16x8 GlA[1024];   // [64 rows][16 slots of 8 bf16], XOR-swizzled
    __shared__ bf16x8 GlB[1024];
    __shared__ int nidx[64][4];

    const int tid  = threadIdx.x;
    const int b    = blockIdx.z;
    const int e0   = blockIdx.x * TILE_E;
    const int lane = tid & 63;
    const int wv   = tid >> 6;
    const int l15  = lane & 15;
    const int kg   = lane >> 4;        // 0..3
    const int o0   = wv * 32;

    const float* xb = x + (long)b * E_TOT * 128;
    float*       yb = y + (long)b * E_TOT * 128;

    // stage neighbor indices
    {
        int e = tid >> 2, s = tid & 3;
        int eg = e0 + e;
        nidx[e][s] = (eg < E_TOT) ? gemm[((long)b * E_TOT + eg) * 4 + s] : 0;
    }

    // ---- staging lambdas (1024 16B-tasks, 4 per thread) ----
    auto stage_self = [&](bf16x8* dst) {
#pragma unroll
        for (int t = 0; t < 4; ++t) {
            int q = t * 256 + tid;
            int e = q >> 4, c8 = q & 15;
            int eg = e0 + e;
            int se = (eg < E_TOT) ? eg : 0;
            const float* p = xb + (long)se * 128 + c8 * 8;
            float4 v0 = *(const float4*)p;
            float4 v1 = *(const float4*)(p + 4);
            bf16x8 r;
            r[0] = (short)f2bf(v0.x); r[1] = (short)f2bf(v0.y);
            r[2] = (short)f2bf(v0.z); r[3] = (short)f2bf(v0.w);
            r[4] = (short)f2bf(v1.x); r[5] = (short)f2bf(v1.y);
            r[6] = (short)f2bf(v1.z); r[7] = (short)f2bf(v1.w);
            dst[(e * 16 + c8) ^ (e & 7)] = r;
        }
    };
    auto stage_pair = [&](bf16x8* dstS, bf16x8* dstD, int ia, int ib) {
#pragma unroll
        for (int t = 0; t < 4; ++t) {
            int q = t * 256 + tid;
            int e = q >> 4, c8 = q & 15;
            int na = nidx[e][ia], nb = nidx[e][ib];
            const float* pa = xb + (long)na * 128 + c8 * 8;
            const float* pb = xb + (long)nb * 128 + c8 * 8;
            float4 a0 = *(const float4*)pa;
            float4 a1 = *(const float4*)(pa + 4);
            float4 b0 = *(const float4*)pb;
            float4 b1 = *(const float4*)(pb + 4);
            const float* ap0 = &a0.x; const float* ap1 = &a1.x;
            const float* bp0 = &b0.x; const float* bp1 = &b1.x;
            bf16x8 rs, rd;
#pragma unroll
            for (int j = 0; j < 4; ++j) {
                float av = ap0[j], bvv = bp0[j];
                rs[j] = (short)f2bf(av + bvv);
                rd[j] = (short)f2bf(fabsf(av - bvv));
            }
#pragma unroll
            for (int j = 0; j < 4; ++j) {
                float av = ap1[j], bvv = bp1[j];
                rs[4 + j] = (short)f2bf(av + bvv);
                rd[4 + j] = (short)f2bf(fabsf(av - bvv));
            }
            int slot = (e * 16 + c8) ^ (e & 7);
            dstS[slot] = rs;
            dstD[slot] = rd;
        }
    };

    f32x4 acc[4][2];
#pragma unroll
    for (int mt = 0; mt < 4; ++mt)
#pragma unroll
        for (int nt = 0; nt < 2; ++nt)
#pragma unroll
            for (int j = 0; j < 4; ++j) acc[mt][nt][j] = 0.f;

    // per-lane W base (shorts): row o = o0 + nt*16 + l15, k = s*128 + ks*32 + kg*8
    const long wb0 = (long)(o0 + l15) * 640 + kg * 8;

    auto compute_chunk = [&](const bf16x8* buf, int s) {
#pragma unroll
        for (int ks = 0; ks < 4; ++ks) {
            bf16x8 bf0 = *(const bf16x8*)(wt + wb0 + s * 128 + ks * 32);
            bf16x8 bf1 = *(const bf16x8*)(wt + wb0 + 16 * 640 + s * 128 + ks * 32);
#pragma unroll
            for (int mt = 0; mt < 4; ++mt) {
                int row = mt * 16 + l15;
                bf16x8 a = buf[row * 16 + (((ks << 2) | kg) ^ (l15 & 7))];
                acc[mt][0] = __builtin_amdgcn_mfma_f32_16x16x32_bf16(a, bf0, acc[mt][0], 0, 0, 0);
                acc[mt][1] = __builtin_amdgcn_mfma_f32_16x16x32_bf16(a, bf1, acc[mt][1], 0, 0, 0);
            }
        }
    };

    // s0
    stage_self(GlA);
    __syncthreads();
    compute_chunk(GlA, 0);
    __syncthreads();
    // s1 (f1+f3) and s3 (|f1-f3|)
    stage_pair(GlA, GlB, 0, 2);
    __syncthreads();
    compute_chunk(GlA, 1);
    compute_chunk(GlB, 3);
    __syncthreads();
    // s2 (f2+f4) and s4 (|f2-f4|)
    stage_pair(GlA, GlB, 1, 3);
    __syncthreads();
    compute_chunk(GlA, 2);
    compute_chunk(GlB, 4);

    // ---- bias, store, inorm partials ----
    float bv0 = bias ? bias[o0 + l15]      : 0.f;
    float bv1 = bias ? bias[o0 + 16 + l15] : 0.f;
    float s1a0 = 0.f, s2a0 = 0.f, s1a1 = 0.f, s2a1 = 0.f;
#pragma unroll
    for (int mt = 0; mt < 4; ++mt) {
        int ebase = e0 + mt * 16 + (kg << 2);
#pragma unroll
        for (int j = 0; j < 4; ++j) {
            if (ebase + j < E_TOT) {
                float v0v = acc[mt][0][j] + bv0;
                float v1v = acc[mt][1][j] + bv1;
                yb[(long)(ebase + j) * 128 + o0 + l15]      = v0v;
                yb[(long)(ebase + j) * 128 + o0 + 16 + l15] = v1v;
                s1a0 += v0v; s2a0 += v0v * v0v;
                s1a1 += v1v; s2a1 += v1v * v1v;
            }
        }
    }
    s1a0 += __shfl_xor(s1a0, 16); s1a0 += __shfl_xor(s1a0, 32);
    s2a0 += __shfl_xor(s2a0, 16); s2a0 += __shfl_xor(s2a0, 32);
    s1a1 += __shfl_xor(s1a1, 16); s1a1 += __shfl_xor(s1a1, 32);
    s2a1 += __shfl_xor(s2a1, 16); s2a1 += __shfl_xor(s2a1, 32);
    if (lane < 16) {
        long pb = ((long)b * NBLK + blockIdx.x) * 128;
        part[(pb + o0 + lane) * 2 + 0]      = s1a0;
        part[(pb + o0 + lane) * 2 + 1]      = s2a0;
        part[(pb + o0 + 16 + lane) * 2 + 0] = s1a1;
        part[(pb + o0 + 16 + lane) * 2 + 1] = s2a1;
    }
}

// ---------------------------------------------------------------------------
// f32 mesh_conv (kept for C=5 / C=3 / C=64 cases)
// ---------------------------------------------------------------------------
template<int C, int O, bool STATS>
__global__ __launch_bounds__(256)
void mesh_conv_k(const float* __restrict__ x, long bstr, int inC, int c0,
                 const int* __restrict__ gemm,
                 const float* __restrict__ w, const float* __restrict__ bias,
                 float* __restrict__ y, long ybstr, int outS, int oOff,
                 float* __restrict__ part)
{
    constexpr int CC = (C >= 16) ? 16 : C;
    constexpr int K  = CC * 5;
    constexpr int NCHUNK = C / CC;
    constexpr int OG = O / 4;
    constexpr int EG = 256 / OG;
    constexpr int ET = TILE_E / EG;

    __shared__ float Wl[K][O];
    __shared__ float Gl[K][TILE_E];
    __shared__ int   nidx[TILE_E][4];
    __shared__ float red[STATS ? (2 * O * (EG + 1)) : 4];

    const int tid = threadIdx.x;
    const int b  = blockIdx.z;
    const int e0 = blockIdx.x * TILE_E;

    {
        int e = tid >> 2, s = tid & 3;
        int eg = e0 + e;
        nidx[e][s] = (eg < E_TOT) ? gemm[((long)b * E_TOT + eg) * 4 + s] : 0;
    }
    __syncthreads();

    const int od  = (tid % OG) * 4;
    const int teB = (tid / OG) * ET;

    float acc[ET][4];
#pragma unroll
    for (int i = 0; i < ET; ++i)
#pragma unroll
        for (int j = 0; j < 4; ++j) acc[i][j] = 0.f;

    const float* xb = x + (long)b * bstr;

    for (int ch = 0; ch < NCHUNK; ++ch) {
        const int cb = ch * CC;
        if constexpr ((K % 4) == 0) {
            constexpr int KQ = K / 4;
            for (int q = tid; q < O * KQ; q += 256) {
                int o = q / KQ, kq = q % KQ;
                float4 wv = *(const float4*)&w[(long)o * C * 5 + cb * 5 + kq * 4];
                const float* wp = &wv.x;
#pragma unroll
                for (int j = 0; j < 4; ++j) Wl[kq * 4 + j][o] = wp[j];
            }
        } else {
            for (int q = tid; q < O * K; q += 256) {
                int o = q / K, k = q % K;
                Wl[k][o] = w[(long)o * C * 5 + cb * 5 + k];
            }
        }
        if constexpr ((CC % 4) == 0) {
            constexpr int CQ = CC / 4;
            for (int q = tid; q < TILE_E * CQ; q += 256) {
                int e = q / CQ, cq = q % CQ;
                int eg = e0 + e;
                int se = (eg < E_TOT) ? eg : 0;
                long cofs = (long)(c0 + cb + cq * 4);
                float4 s0 = *(const float4*)&xb[(long)se * inC + cofs];
                int4 nn = *(const int4*)&nidx[e][0];
                float4 f1 = *(const float4*)&xb[(long)nn.x * inC + cofs];
                float4 f2 = *(const float4*)&xb[(long)nn.y * inC + cofs];
                float4 f3 = *(const float4*)&xb[(long)nn.z * inC + cofs];
                float4 f4 = *(const float4*)&xb[(long)nn.w * inC + cofs];
                const float *p0 = &s0.x, *p1 = &f1.x, *p2 = &f2.x, *p3 = &f3.x, *p4 = &f4.x;
#pragma unroll
                for (int j = 0; j < 4; ++j) {
                    int kb = (cq * 4 + j) * 5;
                    float v1 = p1[j], v2 = p2[j], v3 = p3[j], v4 = p4[j];
                    Gl[kb + 0][e] = p0[j];
                    Gl[kb + 1][e] = v1 + v3;
                    Gl[kb + 2][e] = v2 + v4;
                    Gl[kb + 3][e] = fabsf(v1 - v3);
                    Gl[kb + 4][e] = fabsf(v2 - v4);
                }
            }
        } else {
            for (int q = tid; q < TILE_E * CC; q += 256) {
                int e = q / CC, c = q % CC;
                int eg = e0 + e;
                int se = (eg < E_TOT) ? eg : 0;
                long cofs = (long)(c0 + cb + c);
                float s0 = xb[(long)se * inC + cofs];
                int4 nn = *(const int4*)&nidx[e][0];
                float v1 = xb[(long)nn.x * inC + cofs];
                float v2 = xb[(long)nn.y * inC + cofs];
                float v3 = xb[(long)nn.z * inC + cofs];
                float v4 = xb[(long)nn.w * inC + cofs];
                int kb = c * 5;
                Gl[kb + 0][e] = s0;
                Gl[kb + 1][e] = v1 + v3;
                Gl[kb + 2][e] = v2 + v4;
                Gl[kb + 3][e] = fabsf(v1 - v3);
                Gl[kb + 4][e] = fabsf(v2 - v4);
            }
        }
        __syncthreads();
#pragma unroll 4
        for (int k = 0; k < K; ++k) {
            float4 wv = *(const float4*)&Wl[k][od];
            float g[ET];
            if constexpr (ET >= 4) {
#pragma unroll
                for (int i = 0; i < ET; i += 4) {
                    float4 gv = *(const float4*)&Gl[k][teB + i];
                    g[i] = gv.x; g[i + 1] = gv.y; g[i + 2] = gv.z; g[i + 3] = gv.w;
                }
            } else {
                float2 gv = *(const float2*)&Gl[k][teB];
                g[0] = gv.x; g[1] = gv.y;
            }
#pragma unroll
            for (int i = 0; i < ET; ++i) {
                acc[i][0] = fmaf(g[i], wv.x, acc[i][0]);
                acc[i][1] = fmaf(g[i], wv.y, acc[i][1]);
                acc[i][2] = fmaf(g[i], wv.z, acc[i][2]);
                acc[i][3] = fmaf(g[i], wv.w, acc[i][3]);
            }
        }
        __syncthreads();
    }

    if (bias) {
        float bv[4] = {bias[od], bias[od + 1], bias[od + 2], bias[od + 3]};
#pragma unroll
        for (int i = 0; i < ET; ++i)
#pragma unroll
            for (int j = 0; j < 4; ++j) acc[i][j] += bv[j];
    }

    float* yb = y + (long)b * ybstr;
#pragma unroll
    for (int i = 0; i < ET; ++i) {
        int eg = e0 + teB + i;
        if (eg < E_TOT) {
            float4 v = make_float4(acc[i][0], acc[i][1], acc[i][2], acc[i][3]);
            *(float4*)&yb[(long)eg * outS + oOff + od] = v;
        }
    }

    if constexpr (STATS) {
        const int tg = tid / OG;
        float* red1 = red;
        float* red2 = red + O * (EG + 1);
#pragma unroll
        for (int j = 0; j < 4; ++j) {
            float s1 = 0.f, s2 = 0.f;
#pragma unroll
            for (int i = 0; i < ET; ++i) {
                int eg = e0 + teB + i;
                if (eg < E_TOT) { float v = acc[i][j]; s1 += v; s2 += v * v; }
            }
            red1[(od + j) * (EG + 1) + tg] = s1;
            red2[(od + j) * (EG + 1) + tg] = s2;
        }
        __syncthreads();
        if (tid < O) {
            float s = 0.f;
            for (int t = 0; t < EG; ++t) s += red1[tid * (EG + 1) + t];
            part[(((long)b * NBLK + blockIdx.x) * O + tid) * 2 + 0] = s;
        } else if (tid < 2 * O) {
            int o = tid - O;
            float s = 0.f;
            for (int t = 0; t < EG; ++t) s += red2[o * (EG + 1) + t];
            part[(((long)b * NBLK + blockIdx.x) * O + o) * 2 + 1] = s;
        }
    }
}

// ---------------------------------------------------------------------------
// 1x1 conv (unchanged)
// ---------------------------------------------------------------------------
template<int C, int O, bool STATS>
__global__ __launch_bounds__(256)
void conv1_k(const float* __restrict__ x, long bstr, long estr, long cstr, int c0,
             const float* __restrict__ w, const float* __restrict__ bias,
             float* __restrict__ y, long ybstr, int outS, int oOff,
             float* __restrict__ part)
{
    constexpr int CC = (C >= 32) ? 32 : C;
    constexpr int NCHUNK = C / CC;
    constexpr int OG = O / 4;
    constexpr int EG = 256 / OG;
    constexpr int ET = TILE_E / EG;

    __shared__ float Wl[CC][O];
    __shared__ float Gl[CC][TILE_E];
    __shared__ float red[STATS ? (2 * O * (EG + 1)) : 4];

    const int tid = threadIdx.x;
    const int b  = blockIdx.z;
    const int e0 = blockIdx.x * TILE_E;

    const int od  = (tid % OG) * 4;
    const int teB = (tid / OG) * ET;

    float acc[ET][4];
#pragma unroll
    for (int i = 0; i < ET; ++i)
#pragma unroll
        for (int j = 0; j < 4; ++j) acc[i][j] = 0.f;

    const float* xb = x + (long)b * bstr;

    for (int ch = 0; ch < NCHUNK; ++ch) {
        const int cb = ch * CC;
        {
            constexpr int KQ = CC / 4;
            for (int q = tid; q < O * KQ; q += 256) {
                int o = q / KQ, kq = q % KQ;
                float4 wv = *(const float4*)&w[(long)o * C + cb + kq * 4];
                const float* wp = &wv.x;
#pragma unroll
                for (int j = 0; j < 4; ++j) Wl[kq * 4 + j][o] = wp[j];
            }
        }
        if (cstr == 1) {
            constexpr int CQ = CC / 4;
            for (int q = tid; q < TILE_E * CQ; q += 256) {
                int e = q / CQ, cq = q % CQ;
                int eg = e0 + e;
                int se = (eg < E_TOT) ? eg : 0;
                float4 v = *(const float4*)&xb[(long)se * estr + (c0 + cb + cq * 4)];
                const float* vp = &v.x;
#pragma unroll
                for (int j = 0; j < 4; ++j) Gl[cq * 4 + j][e] = vp[j];
            }
        } else {
            for (int q = tid; q < CC * (TILE_E / 4); q += 256) {
                int c = q / (TILE_E / 4), eq = q % (TILE_E / 4);
                int e4 = e0 + eq * 4;
                float4 v;
                if (e4 + 3 < E_TOT) {
                    v = *(const float4*)&x[(long)b * bstr + (long)(c0 + cb + c) * cstr + e4];
                } else {
                    float* vp = &v.x;
#pragma unroll
                    for (int j = 0; j < 4; ++j) {
                        int ej = e4 + j;
                        vp[j] = (ej < E_TOT)
                              ? x[(long)b * bstr + (long)(c0 + cb + c) * cstr + ej] : 0.f;
                    }
                }
                *(float4*)&Gl[c][eq * 4] = v;
            }
        }
        __syncthreads();
#pragma unroll 4
        for (int k = 0; k < CC; ++k) {
            float4 wv = *(const float4*)&Wl[k][od];
            float g[ET];
            if constexpr (ET >= 4) {
#pragma unroll
                for (int i = 0; i < ET; i += 4) {
                    float4 gv = *(const float4*)&Gl[k][teB + i];
                    g[i] = gv.x; g[i + 1] = gv.y; g[i + 2] = gv.z; g[i + 3] = gv.w;
                }
            } else {
                float2 gv = *(const float2*)&Gl[k][teB];
                g[0] = gv.x; g[1] = gv.y;
            }
#pragma unroll
            for (int i = 0; i < ET; ++i) {
                acc[i][0] = fmaf(g[i], wv.x, acc[i][0]);
                acc[i][1] = fmaf(g[i], wv.y, acc[i][1]);
                acc[i][2] = fmaf(g[i], wv.z, acc[i][2]);
                acc[i][3] = fmaf(g[i], wv.w, acc[i][3]);
            }
        }
        __syncthreads();
    }

    if (bias) {
        float bv[4] = {bias[od], bias[od + 1], bias[od + 2], bias[od + 3]};
#pragma unroll
        for (int i = 0; i < ET; ++i)
#pragma unroll
            for (int j = 0; j < 4; ++j) acc[i][j] += bv[j];
    }

    float* yb = y + (long)b * ybstr;
#pragma unroll
    for (int i = 0; i < ET; ++i) {
        int eg = e0 + teB + i;
        if (eg < E_TOT) {
            float4 v = make_float4(acc[i][0], acc[i][1], acc[i][2], acc[i][3]);
            *(float4*)&yb[(long)eg * outS + oOff + od] = v;
        }
    }

    if constexpr (STATS) {
        const int tg = tid / OG;
        float* red1 = red;
        float* red2 = red + O * (EG + 1);
#pragma unroll
        for (int j = 0; j < 4; ++j) {
            float s1 = 0.f, s2 = 0.f;
#pragma unroll
            for (int i = 0; i < ET; ++i) {
                int eg = e0 + teB + i;
                if (eg < E_TOT) { float v = acc[i][j]; s1 += v; s2 += v * v; }
            }
            red1[(od + j) * (EG + 1) + tg] = s1;
            red2[(od + j) * (EG + 1) + tg] = s2;
        }
        __syncthreads();
        if (tid < O) {
            float s = 0.f;
            for (int t = 0; t < EG; ++t) s += red1[tid * (EG + 1) + t];
            part[(((long)b * NBLK + blockIdx.x) * O + tid) * 2 + 0] = s;
        } else if (tid < 2 * O) {
            int o = tid - O;
            float s = 0.f;
            for (int t = 0; t < EG; ++t) s += red2[o * (EG + 1) + t];
            part[(((long)b * NBLK + blockIdx.x) * O + o) * 2 + 1] = s;
        }
    }
}

// ---------------------------------------------------------------------------
__global__ void stats_fin_k(const float* __restrict__ part, float* __restrict__ stats)
{
    int t = threadIdx.x;
    int b = t >> 7, o = t & 127;
    float s1 = 0.f, s2 = 0.f;
    for (int k = 0; k < NBLK; ++k) {
        long base = (((long)b * NBLK + k) * 128 + o) * 2;
        s1 += part[base];
        s2 += part[base + 1];
    }
    float mean = s1 / (float)E_TOT;
    float var  = s2 / (float)E_TOT - mean * mean;
    var = fmaxf(var, 0.f);
    stats[(b * 128 + o) * 2 + 0] = mean;
    stats[(b * 128 + o) * 2 + 1] = rsqrtf(var + 1e-5f);
}

template<int ACT>
__global__ __launch_bounds__(256)
void norm_act_em_k(const float* __restrict__ xin, const float* __restrict__ stats,
                   float* __restrict__ yout)
{
    long q = (long)blockIdx.x * 256 + threadIdx.x;
    long tot = (long)B_TOT * E_TOT * 128 / 4;
    if (q >= tot) return;
    long idx = q * 4;
    int c = (int)(idx & 127);
    long be = idx >> 7;
    int b = (int)(be / E_TOT);
    float4 v = *(const float4*)&xin[idx];
    float* vp = &v.x;
#pragma unroll
    for (int j = 0; j < 4; ++j) {
        float2 st = *(const float2*)&stats[(b * 128 + c + j) * 2];
        float t = (vp[j] - st.x) * st.y;
        vp[j] = (ACT == 0) ? fmaxf(t, 0.f) : sigmoidf_(t);
    }
    *(float4*)&yout[idx] = v;
}

__global__ __launch_bounds__(256)
void norm_res_cm_k(const float* __restrict__ xin, const float* __restrict__ res,
                   const float* __restrict__ stats, float* __restrict__ outb, int sect)
{
    __shared__ float T[32 * 68];
    int b = blockIdx.z, cg = blockIdx.y;
    int e0 = blockIdx.x * 64;
    int tid = threadIdx.x;
#pragma unroll
    for (int i = 0; i < 2; ++i) {
        int q = tid + i * 256;
        int e = q >> 3, cq = q & 7;
        int eg = e0 + e;
        int se = (eg < E_TOT) ? eg : (E_TOT - 1);
        int c = cg * 32 + cq * 4;
        long base = ((long)b * E_TOT + se) * 128 + c;
        float4 v = *(const float4*)&xin[base];
        float4 r = *(const float4*)&res[base];
        float* vp = &v.x; float* rp = &r.x;
#pragma unroll
        for (int j = 0; j < 4; ++j) {
            float2 st = *(const float2*)&stats[(b * 128 + c + j) * 2];
            float t = (vp[j] - st.x) * st.y + rp[j];
            T[(cq * 4 + j) * 68 + e] = fmaxf(t, 0.f);
        }
    }
    __syncthreads();
#pragma unroll
    for (int i = 0; i < 2; ++i) {
        int q = tid + i * 256;
        int cl = q >> 4, eq = q & 15;
        int e4 = e0 + eq * 4;
        int cglob = sect + cg * 32 + cl;
        float4 v = *(const float4*)&T[cl * 68 + eq * 4];
        long obase = ((long)b * 384 + cglob) * E_TOT + e4;
        if (e4 + 3 < E_TOT) {
            *(float4*)&outb[obase] = v;
        } else {
            const float* vp = &v.x;
            for (int j = 0; j < 4; ++j)
                if (e4 + j < E_TOT) outb[obase + j] = vp[j];
        }
    }
}

__global__ __launch_bounds__(256)
void final_agg_k(const float* __restrict__ wA, const float* __restrict__ wB,
                 float* __restrict__ outb)
{
    __shared__ float S[32 * 68];
    int b = blockIdx.z, cg = blockIdx.y;
    int e0 = blockIdx.x * 64;
    int tid = threadIdx.x;
#pragma unroll
    for (int i = 0; i < 2; ++i) {
        int q = tid + i * 256;
        int e = q >> 3, cq = q & 7;
        int eg = e0 + e;
        int se = (eg < E_TOT) ? eg : (E_TOT - 1);
        int c = cg * 32 + cq * 4;
        long base = ((long)b * E_TOT + se) * 128 + c;
        float4 a = *(const float4*)&wA[base];
        float4 bb = *(const float4*)&wB[base];
        const float* ap = &a.x; const float* bp = &bb.x;
#pragma unroll
        for (int j = 0; j < 4; ++j)
            S[(cq * 4 + j) * 68 + e] = sigmoidf_(ap[j] - bp[j]);
    }
    __syncthreads();
#pragma unroll
    for (int i = 0; i < 2; ++i) {
        int q = tid + i * 256;
        int cl = q >> 4, eq = q & 15;
        int e4 = e0 + eq * 4;
        int cglob = cg * 32 + cl;
        float4 s = *(const float4*)&S[cl * 68 + eq * 4];
        long eb = ((long)b * 384 + cglob) * E_TOT + e4;
        long pb = ((long)b * 384 + 128 + cglob) * E_TOT + e4;
        long ab = ((long)b * 384 + 256 + cglob) * E_TOT + e4;
        if (e4 + 3 < E_TOT) {
            float4 xe = *(const float4*)&outb[eb];
            float4 xp = *(const float4*)&outb[pb];
            float* sp = &s.x; float* xep = &xe.x; float* xpp = &xp.x;
            float4 r;
            float* rp = &r.x;
#pragma unroll
            for (int j = 0; j < 4; ++j)
                rp[j] = xep[j] * sp[j] + xpp[j] * (1.f - sp[j]);
            *(float4*)&outb[ab] = r;
        } else {
            const float* sp = &s.x;
            for (int j = 0; j < 4; ++j) {
                if (e4 + j < E_TOT) {
                    float xe = outb[eb + j], xp = outb[pb + j];
                    outb[ab + j] = xe * sp[j] + xp * (1.f - sp[j]);
                }
            }
        }
    }
}

// ---------------------------------------------------------------------------
extern "C" void kernel_launch(void* const* d_in, const int* in_sizes, int n_in,
                              void* d_out, int out_size, void* d_ws, size_t ws_size,
                              hipStream_t stream)
{
    const float* fe   = (const float*)d_in[0];
    const int*   gemm = (const int*)  d_in[1];
    const float* w_e1 = (const float*)d_in[2];  const float* b_e1 = (const float*)d_in[3];
    const float* w_p1 = (const float*)d_in[4];  const float* b_p1 = (const float*)d_in[5];
    const float* w_e2 = (const float*)d_in[6];  const float* b_e2 = (const float*)d_in[7];
    const float* w_p2 = (const float*)d_in[8];  const float* b_p2 = (const float*)d_in[9];
    const float* wa   = (const float*)d_in[10]; const float* ba   = (const float*)d_in[11];
    const float* wb   = (const float*)d_in[12]; const float* bb   = (const float*)d_in[13];
    const float* wal  = (const float*)d_in[14]; const float* bal  = (const float*)d_in[15];
    const float* wbl  = (const float*)d_in[16]; const float* bbl  = (const float*)d_in[17];
    const float* wat  = (const float*)d_in[18]; const float* bat  = (const float*)d_in[19];
    const float* wbt  = (const float*)d_in[20]; const float* bbt  = (const float*)d_in[21];
    const float* waf  = (const float*)d_in[22]; const float* baf  = (const float*)d_in[23];
    const float* wbf  = (const float*)d_in[24]; const float* bbf  = (const float*)d_in[25];
    float* out = (float*)d_out;

    const long EB = (long)E_TOT;
    // workspace layout (floats)
    float* FET = (float*)d_ws;                       // B*E*8
    float* X1  = FET + (long)B_TOT * EB * 8;         // B*E*128
    float* TMP = X1  + (long)B_TOT * EB * 128;       // B*E*128
    float* XA2 = TMP + (long)B_TOT * EB * 128;       // B*E*128
    float* XB2 = XA2 + (long)B_TOT * EB * 128;       // B*E*128
    float* PART  = XB2 + (long)B_TOT * EB * 128;     // B*NBLK*128*2
    float* STATS = PART + (long)B_TOT * NBLK * 128 * 2;   // B*128*2
    float* WTF   = STATS + (long)B_TOT * 128 * 2;    // 2 * 128*640 bf16 = 2*40960 floats
    unsigned short* WT_E2 = (unsigned short*)WTF;
    unsigned short* WT_P2 = WT_E2 + 128 * 640;

    const size_t ws_need = (size_t)((WTF + 2 * 40960) - FET) * sizeof(float);
    if (ws_size < ws_need) {
        fprintf(stderr, "kernel_launch: ws too small (%zu < %zu)\n", ws_size, ws_need);
        return;
    }

    dim3 blk(256);
    dim3 gE(NBLK, 1, B_TOT);
    dim3 gT((E_TOT + 255) / 256, 1, B_TOT);
    dim3 gN(NBLK, 4, B_TOT);
    long nq = (long)B_TOT * E_TOT * 128 / 4;
    int gEW = (int)((nq + 255) / 256);

    transpose_in_k<<<gT, blk, 0, stream>>>(fe, FET);
    wtrans_k<<<320, blk, 0, stream>>>(w_e2, WT_E2);
    wtrans_k<<<320, blk, 0, stream>>>(w_p2, WT_P2);

    // ---- edge branch
    mesh_conv_k<5, 128, true><<<gE, blk, 0, stream>>>(FET, EB * 8, 8, 0, gemm,
        w_e1, b_e1, TMP, EB * 128, 128, 0, PART);
    stats_fin_k<<<1, 256, 0, stream>>>(PART, STATS);
    norm_act_em_k<0><<<gEW, blk, 0, stream>>>(TMP, STATS, X1);          // x1_e
    mesh_conv_mfma_k<<<gE, blk, 0, stream>>>(X1, gemm, WT_E2, b_e2, TMP, PART);
    stats_fin_k<<<1, 256, 0, stream>>>(PART, STATS);
    norm_res_cm_k<<<gN, blk, 0, stream>>>(TMP, X1, STATS, out, 0);      // x2_e

    // ---- point branch
    mesh_conv_k<3, 128, true><<<gE, blk, 0, stream>>>(FET, EB * 8, 8, 5, gemm,
        w_p1, b_p1, TMP, EB * 128, 128, 0, PART);
    stats_fin_k<<<1, 256, 0, stream>>>(PART, STATS);
    norm_act_em_k<0><<<gEW, blk, 0, stream>>>(TMP, STATS, X1);          // x1_p
    mesh_conv_mfma_k<<<gE, blk, 0, stream>>>(X1, gemm, WT_P2, b_p2, TMP, PART);
    stats_fin_k<<<1, 256, 0, stream>>>(PART, STATS);
    norm_res_cm_k<<<gN, blk, 0, stream>>>(TMP, X1, STATS, out, 128);    // x2_p

    // ---- x_all = concat(conv1(x2e,wa), conv1(x2p,wb))
    conv1_k<128, 32, false><<<gE, blk, 0, stream>>>(out, (long)384 * E_TOT, 1, EB, 0,
        wa, ba, X1, EB * 64, 64, 0, nullptr);
    conv1_k<128, 32, false><<<gE, blk, 0, stream>>>(out, (long)384 * E_TOT, 1, EB, 128,
        wb, bb, X1, EB * 64, 64, 32, nullptr);

    // ---- two-branch heads
    conv1_k<64, 64, false><<<gE, blk, 0, stream>>>(X1, EB * 64, 64, 1, 0,
        wal, bal, XA2, EB * 128, 128, 0, nullptr);
    mesh_conv_k<64, 64, false><<<gE, blk, 0, stream>>>(X1, EB * 64, 64, 0, gemm,
        wat, bat, XA2, EB * 128, 128, 64, nullptr);
    conv1_k<64, 64, false><<<gE, blk, 0, stream>>>(X1, EB * 64, 64, 1, 0,
        wbl, bbl, XB2, EB * 128, 128, 0, nullptr);
    mesh_conv_k<64, 64, false><<<gE, blk, 0, stream>>>(X1, EB * 64, 64, 0, gemm,
        wbt, bbt, XB2, EB * 128, 128, 64, nullptr);

    // ---- gates
    conv1_k<128, 128, true><<<gE, blk, 0, stream>>>(XA2, EB * 128, 128, 1, 0,
        waf, baf, TMP, EB * 128, 128, 0, PART);
    stats_fin_k<<<1, 256, 0, stream>>>(PART, STATS);
    norm_act_em_k<1><<<gEW, blk, 0, stream>>>(TMP, STATS, XA2);         // wA
    conv1_k<128, 128, true><<<gE, blk, 0, stream>>>(XB2, EB * 128, 128, 1, 0,
        wbf, bbf, TMP, EB * 128, 128, 0, PART);
    stats_fin_k<<<1, 256, 0, stream>>>(PART, STATS);
    norm_act_em_k<1><<<gEW, blk, 0, stream>>>(TMP, STATS, XB2);         // wB

    // ---- aggregate
    final_agg_k<<<gN, blk, 0, stream>>>(XA2, XB2, out);
}

// Round 3
// 492.759 us; speedup vs baseline: 2.9334x; 1.8340x over previous
//
#include <hip/hip_runtime.h>
#include <cstdio>
#include <math.h>

// ---------------------------------------------------------------------------
// MeshEncoderDecoder — round 3: MFMA everywhere GEMM-shaped; bf16 activations.
// ---------------------------------------------------------------------------

#define E_TOT 50000
#define B_TOT 2
#define TILE_E 64
#define NBLK ((E_TOT + TILE_E - 1) / TILE_E)   // 782

typedef __attribute__((ext_vector_type(8))) short bf16x8;
typedef __attribute__((ext_vector_type(8))) unsigned short us8;
typedef __attribute__((ext_vector_type(4))) float f32x4;
typedef unsigned short ushort_t;

__device__ __forceinline__ float sigmoidf_(float x) {
    return 1.0f / (1.0f + __expf(-x));
}
__device__ __forceinline__ unsigned short f2bf(float f) {
    unsigned int u = __float_as_uint(f);
    unsigned int r = (u + 0x7fffu + ((u >> 16) & 1u)) >> 16;
    return (unsigned short)r;
}
__device__ __forceinline__ float bf2f(unsigned short u) {
    return __uint_as_float(((unsigned int)u) << 16);
}

// ---------------------------------------------------------------------------
// transpose fe (b, 8, E) -> fe_t (b, E, 8)
// ---------------------------------------------------------------------------
__global__ __launch_bounds__(256)
void transpose_in_k(const float* __restrict__ fe, float* __restrict__ fet)
{
    int b = blockIdx.z;
    int e = blockIdx.x * 256 + threadIdx.x;
    if (e >= E_TOT) return;
    float v[8];
#pragma unroll
    for (int c = 0; c < 8; ++c)
        v[c] = fe[((long)b * 8 + c) * E_TOT + e];
    float4* dst = (float4*)&fet[((long)b * E_TOT + e) * 8];
    dst[0] = make_float4(v[0], v[1], v[2], v[3]);
    dst[1] = make_float4(v[4], v[5], v[6], v[7]);
}

// ---------------------------------------------------------------------------
// mesh weight transform: w [O][C][5] f32 -> wt [(o*5+s)*C + c] bf16
// ---------------------------------------------------------------------------
template<int C, int O>
__global__ __launch_bounds__(256)
void wtrans_mesh_k(const float* __restrict__ w, ushort_t* __restrict__ wt)
{
    int idx = blockIdx.x * 256 + threadIdx.x;
    if (idx >= O * 5 * C) return;
    int o = idx / (5 * C);
    int r = idx % (5 * C);
    int s = r / C, c = r % C;
    wt[idx] = f2bf(w[((long)o * C + c) * 5 + s]);
}

__global__ __launch_bounds__(256)
void cast_bf16_k(const float* __restrict__ src, ushort_t* __restrict__ dst, int n)
{
    int i = blockIdx.x * 256 + threadIdx.x;
    if (i < n) dst[i] = f2bf(src[i]);
}

// ---------------------------------------------------------------------------
// MFMA mesh conv: x bf16 edge-major [b][E][C] (batch stride xbstr shorts),
// wt bf16 [(o*5+s)*C+c], y f32 edge-major [b][E][outS] col oOff.
// Block: 64 edges x O outs, 256 threads / 4 waves.
// ---------------------------------------------------------------------------
template<int C, int O, bool STATS>
__global__ __launch_bounds__(256)
void mesh_mfma_k(const ushort_t* __restrict__ x, long xbstr,
                 const int* __restrict__ gemm,
                 const ushort_t* __restrict__ wt, const float* __restrict__ bias,
                 float* __restrict__ y, long ybstr, int outS, int oOff,
                 float* __restrict__ part)
{
    constexpr int SL = C / 8;       // 16B slots per row
    constexpr int NT = O / 64;      // o-frags per wave
    constexpr int KS = C / 32;      // K-steps per feature
    constexpr int T  = (64 * SL) / 256;

    __shared__ bf16x8 GlA[64 * SL];
    __shared__ bf16x8 GlB[64 * SL];
    __shared__ int nidx[64][4];

    const int tid  = threadIdx.x;
    const int b    = blockIdx.z;
    const int e0   = blockIdx.x * TILE_E;
    const int lane = tid & 63;
    const int wv   = tid >> 6;
    const int l15  = lane & 15;
    const int kg   = lane >> 4;
    const int o0   = wv * (O / 4);

    const ushort_t* xb = x + (long)b * xbstr;
    float*          yb = y + (long)b * ybstr;

    {
        int e = tid >> 2, s = tid & 3;
        int eg = e0 + e;
        nidx[e][s] = (eg < E_TOT) ? gemm[((long)b * E_TOT + eg) * 4 + s] : 0;
    }

    auto stage_self = [&](bf16x8* dst) {
#pragma unroll
        for (int t = 0; t < T; ++t) {
            int q = t * 256 + tid;
            int e = q / SL, c8 = q % SL;
            int eg = e0 + e;
            int se = (eg < E_TOT) ? eg : 0;
            bf16x8 r = *(const bf16x8*)(xb + (long)se * C + c8 * 8);
            dst[(e * SL + c8) ^ (e & 7)] = r;
        }
    };
    auto stage_pair = [&](bf16x8* dstS, bf16x8* dstD, int ia, int ib) {
#pragma unroll
        for (int t = 0; t < T; ++t) {
            int q = t * 256 + tid;
            int e = q / SL, c8 = q % SL;
            int na = nidx[e][ia], nb = nidx[e][ib];
            bf16x8 a = *(const bf16x8*)(xb + (long)na * C + c8 * 8);
            bf16x8 bq = *(const bf16x8*)(xb + (long)nb * C + c8 * 8);
            bf16x8 rs, rd;
#pragma unroll
            for (int j = 0; j < 8; ++j) {
                float av = bf2f((unsigned short)a[j]);
                float bv = bf2f((unsigned short)bq[j]);
                rs[j] = (short)f2bf(av + bv);
                rd[j] = (short)f2bf(fabsf(av - bv));
            }
            int slot = (e * SL + c8) ^ (e & 7);
            dstS[slot] = rs;
            dstD[slot] = rd;
        }
    };

    f32x4 acc[4][NT];
#pragma unroll
    for (int mt = 0; mt < 4; ++mt)
#pragma unroll
        for (int nt = 0; nt < NT; ++nt)
#pragma unroll
            for (int j = 0; j < 4; ++j) acc[mt][nt][j] = 0.f;

    auto compute_chunk = [&](const bf16x8* buf, int s) {
#pragma unroll
        for (int ks = 0; ks < KS; ++ks) {
            bf16x8 bw[NT];
#pragma unroll
            for (int nt = 0; nt < NT; ++nt)
                bw[nt] = *(const bf16x8*)(wt + ((long)(o0 + nt * 16 + l15) * 5 + s) * C + ks * 32 + kg * 8);
#pragma unroll
            for (int mt = 0; mt < 4; ++mt) {
                int row = mt * 16 + l15;
                bf16x8 a = buf[row * SL + ((ks * 4 + kg) ^ (l15 & 7))];
#pragma unroll
                for (int nt = 0; nt < NT; ++nt)
                    acc[mt][nt] = __builtin_amdgcn_mfma_f32_16x16x32_bf16(a, bw[nt], acc[mt][nt], 0, 0, 0);
            }
        }
    };

    stage_self(GlA);
    __syncthreads();
    compute_chunk(GlA, 0);
    __syncthreads();
    stage_pair(GlA, GlB, 0, 2);   // s1=f1+f3, s3=|f1-f3|
    __syncthreads();
    compute_chunk(GlA, 1);
    compute_chunk(GlB, 3);
    __syncthreads();
    stage_pair(GlA, GlB, 1, 3);   // s2=f2+f4, s4=|f2-f4|
    __syncthreads();
    compute_chunk(GlA, 2);
    compute_chunk(GlB, 4);

    float bv[NT], s1[NT], s2[NT];
#pragma unroll
    for (int nt = 0; nt < NT; ++nt) {
        bv[nt] = bias ? bias[o0 + nt * 16 + l15] : 0.f;
        s1[nt] = 0.f; s2[nt] = 0.f;
    }
#pragma unroll
    for (int mt = 0; mt < 4; ++mt) {
        int ebase = e0 + mt * 16 + (kg << 2);
#pragma unroll
        for (int j = 0; j < 4; ++j) {
            if (ebase + j < E_TOT) {
#pragma unroll
                for (int nt = 0; nt < NT; ++nt) {
                    float v = acc[mt][nt][j] + bv[nt];
                    yb[(long)(ebase + j) * outS + oOff + o0 + nt * 16 + l15] = v;
                    if constexpr (STATS) { s1[nt] += v; s2[nt] += v * v; }
                }
            }
        }
    }
    if constexpr (STATS) {
#pragma unroll
        for (int nt = 0; nt < NT; ++nt) {
            s1[nt] += __shfl_xor(s1[nt], 16); s1[nt] += __shfl_xor(s1[nt], 32);
            s2[nt] += __shfl_xor(s2[nt], 16); s2[nt] += __shfl_xor(s2[nt], 32);
        }
        if (lane < 16) {
            long pb = ((long)b * NBLK + blockIdx.x) * O;
#pragma unroll
            for (int nt = 0; nt < NT; ++nt) {
                part[(pb + o0 + nt * 16 + lane) * 2 + 0] = s1[nt];
                part[(pb + o0 + nt * 16 + lane) * 2 + 1] = s2[nt];
            }
        }
    }
}

// ---------------------------------------------------------------------------
// MFMA 1x1 conv. x edge-major [b][E][C] (f32 or bf16), y edge-major (f32 or bf16).
// O>=64: 4 waves split o. O==32: 4 waves split edges (16 each).
// ---------------------------------------------------------------------------
template<int C, int O, bool STATS, bool BF16IN, bool BF16OUT>
__global__ __launch_bounds__(256)
void conv1_mfma_k(const void* __restrict__ xv, long xbstr,
                  const ushort_t* __restrict__ wt, const float* __restrict__ bias,
                  void* __restrict__ yv, long ybstr, int outS, int oOff,
                  float* __restrict__ part)
{
    constexpr int SL = C / 8;
    constexpr int KS = C / 32;
    constexpr int T  = (64 * SL) / 256;
    constexpr int NT = (O >= 64) ? (O / 64) : 2;
    constexpr int MT = (O >= 64) ? 4 : 1;

    __shared__ bf16x8 Gl[64 * SL];

    const int tid  = threadIdx.x;
    const int b    = blockIdx.z;
    const int e0   = blockIdx.x * TILE_E;
    const int lane = tid & 63;
    const int wv   = tid >> 6;
    const int l15  = lane & 15;
    const int kg   = lane >> 4;
    const int o0   = (O >= 64) ? wv * (O / 4) : 0;
    const int eoff = (O >= 64) ? 0 : wv * 16;

    // ---- stage
    if constexpr (BF16IN) {
        const ushort_t* xb = (const ushort_t*)xv + (long)b * xbstr;
#pragma unroll
        for (int t = 0; t < T; ++t) {
            int q = t * 256 + tid;
            int e = q / SL, c8 = q % SL;
            int eg = e0 + e;
            int se = (eg < E_TOT) ? eg : 0;
            bf16x8 r = *(const bf16x8*)(xb + (long)se * C + c8 * 8);
            Gl[(e * SL + c8) ^ (e & 7)] = r;
        }
    } else {
        const float* xb = (const float*)xv + (long)b * xbstr;
#pragma unroll
        for (int t = 0; t < T; ++t) {
            int q = t * 256 + tid;
            int e = q / SL, c8 = q % SL;
            int eg = e0 + e;
            int se = (eg < E_TOT) ? eg : 0;
            const float* p = xb + (long)se * C + c8 * 8;
            float4 v0 = *(const float4*)p;
            float4 v1 = *(const float4*)(p + 4);
            bf16x8 r;
            r[0] = (short)f2bf(v0.x); r[1] = (short)f2bf(v0.y);
            r[2] = (short)f2bf(v0.z); r[3] = (short)f2bf(v0.w);
            r[4] = (short)f2bf(v1.x); r[5] = (short)f2bf(v1.y);
            r[6] = (short)f2bf(v1.z); r[7] = (short)f2bf(v1.w);
            Gl[(e * SL + c8) ^ (e & 7)] = r;
        }
    }
    __syncthreads();

    f32x4 acc[MT][NT];
#pragma unroll
    for (int mt = 0; mt < MT; ++mt)
#pragma unroll
        for (int nt = 0; nt < NT; ++nt)
#pragma unroll
            for (int j = 0; j < 4; ++j) acc[mt][nt][j] = 0.f;

#pragma unroll
    for (int ks = 0; ks < KS; ++ks) {
        bf16x8 bw[NT];
#pragma unroll
        for (int nt = 0; nt < NT; ++nt)
            bw[nt] = *(const bf16x8*)(wt + (long)(o0 + nt * 16 + l15) * C + ks * 32 + kg * 8);
#pragma unroll
        for (int mt = 0; mt < MT; ++mt) {
            int row = eoff + mt * 16 + l15;
            bf16x8 a = Gl[row * SL + ((ks * 4 + kg) ^ (row & 7))];
#pragma unroll
            for (int nt = 0; nt < NT; ++nt)
                acc[mt][nt] = __builtin_amdgcn_mfma_f32_16x16x32_bf16(a, bw[nt], acc[mt][nt], 0, 0, 0);
        }
    }

    float bv[NT], s1[NT], s2[NT];
#pragma unroll
    for (int nt = 0; nt < NT; ++nt) {
        bv[nt] = bias ? bias[o0 + nt * 16 + l15] : 0.f;
        s1[nt] = 0.f; s2[nt] = 0.f;
    }
#pragma unroll
    for (int mt = 0; mt < MT; ++mt) {
        int ebase = e0 + eoff + mt * 16 + (kg << 2);
#pragma unroll
        for (int j = 0; j < 4; ++j) {
            if (ebase + j < E_TOT) {
#pragma unroll
                for (int nt = 0; nt < NT; ++nt) {
                    float v = acc[mt][nt][j] + bv[nt];
                    long oidx = (long)(ebase + j) * outS + oOff + o0 + nt * 16 + l15;
                    if constexpr (BF16OUT)
                        ((ushort_t*)yv)[(long)b * ybstr + oidx] = f2bf(v);
                    else
                        ((float*)yv)[(long)b * ybstr + oidx] = v;
                    if constexpr (STATS) { s1[nt] += v; s2[nt] += v * v; }
                }
            }
        }
    }
    if constexpr (STATS) {
#pragma unroll
        for (int nt = 0; nt < NT; ++nt) {
            s1[nt] += __shfl_xor(s1[nt], 16); s1[nt] += __shfl_xor(s1[nt], 32);
            s2[nt] += __shfl_xor(s2[nt], 16); s2[nt] += __shfl_xor(s2[nt], 32);
        }
        if (lane < 16) {
            long pb = ((long)b * NBLK + blockIdx.x) * O;
#pragma unroll
            for (int nt = 0; nt < NT; ++nt) {
                part[(pb + o0 + nt * 16 + lane) * 2 + 0] = s1[nt];
                part[(pb + o0 + nt * 16 + lane) * 2 + 1] = s2[nt];
            }
        }
    }
}

// ---------------------------------------------------------------------------
// f32 mesh_conv (layer-1: C=5 / C=3, from FET)
// ---------------------------------------------------------------------------
template<int C, int O, bool STATS>
__global__ __launch_bounds__(256)
void mesh_conv_k(const float* __restrict__ x, long bstr, int inC, int c0,
                 const int* __restrict__ gemm,
                 const float* __restrict__ w, const float* __restrict__ bias,
                 float* __restrict__ y, long ybstr, int outS, int oOff,
                 float* __restrict__ part)
{
    constexpr int CC = (C >= 16) ? 16 : C;
    constexpr int K  = CC * 5;
    constexpr int NCHUNK = C / CC;
    constexpr int OG = O / 4;
    constexpr int EG = 256 / OG;
    constexpr int ET = TILE_E / EG;

    __shared__ float Wl[K][O];
    __shared__ float Gl[K][TILE_E];
    __shared__ int   nidx[TILE_E][4];
    __shared__ float red[STATS ? (2 * O * (EG + 1)) : 4];

    const int tid = threadIdx.x;
    const int b  = blockIdx.z;
    const int e0 = blockIdx.x * TILE_E;

    {
        int e = tid >> 2, s = tid & 3;
        int eg = e0 + e;
        nidx[e][s] = (eg < E_TOT) ? gemm[((long)b * E_TOT + eg) * 4 + s] : 0;
    }
    __syncthreads();

    const int od  = (tid % OG) * 4;
    const int teB = (tid / OG) * ET;

    float acc[ET][4];
#pragma unroll
    for (int i = 0; i < ET; ++i)
#pragma unroll
        for (int j = 0; j < 4; ++j) acc[i][j] = 0.f;

    const float* xb = x + (long)b * bstr;

    for (int ch = 0; ch < NCHUNK; ++ch) {
        const int cb = ch * CC;
        if constexpr ((K % 4) == 0) {
            constexpr int KQ = K / 4;
            for (int q = tid; q < O * KQ; q += 256) {
                int o = q / KQ, kq = q % KQ;
                float4 wv = *(const float4*)&w[(long)o * C * 5 + cb * 5 + kq * 4];
                const float* wp = &wv.x;
#pragma unroll
                for (int j = 0; j < 4; ++j) Wl[kq * 4 + j][o] = wp[j];
            }
        } else {
            for (int q = tid; q < O * K; q += 256) {
                int o = q / K, k = q % K;
                Wl[k][o] = w[(long)o * C * 5 + cb * 5 + k];
            }
        }
        for (int q = tid; q < TILE_E * CC; q += 256) {
            int e = q / CC, c = q % CC;
            int eg = e0 + e;
            int se = (eg < E_TOT) ? eg : 0;
            long cofs = (long)(c0 + cb + c);
            float s0 = xb[(long)se * inC + cofs];
            int4 nn = *(const int4*)&nidx[e][0];
            float v1 = xb[(long)nn.x * inC + cofs];
            float v2 = xb[(long)nn.y * inC + cofs];
            float v3 = xb[(long)nn.z * inC + cofs];
            float v4 = xb[(long)nn.w * inC + cofs];
            int kb = c * 5;
            Gl[kb + 0][e] = s0;
            Gl[kb + 1][e] = v1 + v3;
            Gl[kb + 2][e] = v2 + v4;
            Gl[kb + 3][e] = fabsf(v1 - v3);
            Gl[kb + 4][e] = fabsf(v2 - v4);
        }
        __syncthreads();
#pragma unroll 4
        for (int k = 0; k < K; ++k) {
            float4 wv = *(const float4*)&Wl[k][od];
            float g[ET];
            if constexpr (ET >= 4) {
#pragma unroll
                for (int i = 0; i < ET; i += 4) {
                    float4 gv = *(const float4*)&Gl[k][teB + i];
                    g[i] = gv.x; g[i + 1] = gv.y; g[i + 2] = gv.z; g[i + 3] = gv.w;
                }
            } else {
                float2 gv = *(const float2*)&Gl[k][teB];
                g[0] = gv.x; g[1] = gv.y;
            }
#pragma unroll
            for (int i = 0; i < ET; ++i) {
                acc[i][0] = fmaf(g[i], wv.x, acc[i][0]);
                acc[i][1] = fmaf(g[i], wv.y, acc[i][1]);
                acc[i][2] = fmaf(g[i], wv.z, acc[i][2]);
                acc[i][3] = fmaf(g[i], wv.w, acc[i][3]);
            }
        }
        __syncthreads();
    }

    if (bias) {
        float bvv[4] = {bias[od], bias[od + 1], bias[od + 2], bias[od + 3]};
#pragma unroll
        for (int i = 0; i < ET; ++i)
#pragma unroll
            for (int j = 0; j < 4; ++j) acc[i][j] += bvv[j];
    }

    float* yb = y + (long)b * ybstr;
#pragma unroll
    for (int i = 0; i < ET; ++i) {
        int eg = e0 + teB + i;
        if (eg < E_TOT) {
            float4 v = make_float4(acc[i][0], acc[i][1], acc[i][2], acc[i][3]);
            *(float4*)&yb[(long)eg * outS + oOff + od] = v;
        }
    }

    if constexpr (STATS) {
        const int tg = tid / OG;
        float* red1 = red;
        float* red2 = red + O * (EG + 1);
#pragma unroll
        for (int j = 0; j < 4; ++j) {
            float s1 = 0.f, s2 = 0.f;
#pragma unroll
            for (int i = 0; i < ET; ++i) {
                int eg = e0 + teB + i;
                if (eg < E_TOT) { float v = acc[i][j]; s1 += v; s2 += v * v; }
            }
            red1[(od + j) * (EG + 1) + tg] = s1;
            red2[(od + j) * (EG + 1) + tg] = s2;
        }
        __syncthreads();
        if (tid < O) {
            float s = 0.f;
            for (int t = 0; t < EG; ++t) s += red1[tid * (EG + 1) + t];
            part[(((long)b * NBLK + blockIdx.x) * O + tid) * 2 + 0] = s;
        } else if (tid < 2 * O) {
            int o = tid - O;
            float s = 0.f;
            for (int t = 0; t < EG; ++t) s += red2[o * (EG + 1) + t];
            part[(((long)b * NBLK + blockIdx.x) * O + o) * 2 + 1] = s;
        }
    }
}

// ---------------------------------------------------------------------------
// parallel stats finalize: one block per (b,o)
// ---------------------------------------------------------------------------
__global__ __launch_bounds__(256)
void stats_fin2_k(const float* __restrict__ part, float* __restrict__ stats)
{
    int b = blockIdx.x >> 7, o = blockIdx.x & 127;
    int tid = threadIdx.x;
    float s1 = 0.f, s2 = 0.f;
    for (int k = tid; k < NBLK; k += 256) {
        long base = (((long)b * NBLK + k) * 128 + o) * 2;
        s1 += part[base];
        s2 += part[base + 1];
    }
#pragma unroll
    for (int d = 1; d < 64; d <<= 1) {
        s1 += __shfl_xor(s1, d);
        s2 += __shfl_xor(s2, d);
    }
    __shared__ float r1[4], r2[4];
    int wv = tid >> 6;
    if ((tid & 63) == 0) { r1[wv] = s1; r2[wv] = s2; }
    __syncthreads();
    if (tid == 0) {
        s1 = r1[0] + r1[1] + r1[2] + r1[3];
        s2 = r2[0] + r2[1] + r2[2] + r2[3];
        float mean = s1 / (float)E_TOT;
        float var  = s2 / (float)E_TOT - mean * mean;
        var = fmaxf(var, 0.f);
        stats[(b * 128 + o) * 2 + 0] = mean;
        stats[(b * 128 + o) * 2 + 1] = rsqrtf(var + 1e-5f);
    }
}

// ---------------------------------------------------------------------------
// norm + activation, f32 in edge-major -> bf16 out edge-major. ACT 0=relu 1=sigmoid
// ---------------------------------------------------------------------------
template<int ACT>
__global__ __launch_bounds__(256)
void norm_act_k(const float* __restrict__ xin, const float* __restrict__ stats,
                ushort_t* __restrict__ yout)
{
    long q = (long)blockIdx.x * 256 + threadIdx.x;
    long tot = (long)B_TOT * E_TOT * 128 / 8;
    if (q >= tot) return;
    long idx = q * 8;
    int c = (int)(idx & 127);
    int b = (int)((idx >> 7) / E_TOT);
    float4 v0 = *(const float4*)&xin[idx];
    float4 v1 = *(const float4*)&xin[idx + 4];
    float vv[8] = {v0.x, v0.y, v0.z, v0.w, v1.x, v1.y, v1.z, v1.w};
    us8 r;
#pragma unroll
    for (int j = 0; j < 8; ++j) {
        float2 st = *(const float2*)&stats[(b * 128 + c + j) * 2];
        float t = (vv[j] - st.x) * st.y;
        t = (ACT == 0) ? fmaxf(t, 0.f) : sigmoidf_(t);
        r[j] = f2bf(t);
    }
    *(us8*)&yout[idx] = r;
}

// ---------------------------------------------------------------------------
// x2 = relu(inorm(tmp) + res_bf16): write f32 channel-major into out section,
// plus bf16 edge-major copy into x2b.
// ---------------------------------------------------------------------------
__global__ __launch_bounds__(256)
void norm_res_cm_k(const float* __restrict__ xin, const ushort_t* __restrict__ res,
                   const float* __restrict__ stats, float* __restrict__ outb, int sect,
                   ushort_t* __restrict__ x2b)
{
    __shared__ float T[32 * 68];
    int b = blockIdx.z, cg = blockIdx.y;
    int e0 = blockIdx.x * 64;
    int tid = threadIdx.x;
#pragma unroll
    for (int i = 0; i < 2; ++i) {
        int q = tid + i * 256;
        int e = q >> 3, cq = q & 7;
        int eg = e0 + e;
        int se = (eg < E_TOT) ? eg : (E_TOT - 1);
        int c = cg * 32 + cq * 4;
        long base = ((long)b * E_TOT + se) * 128 + c;
        float4 v = *(const float4*)&xin[base];
        ushort4 r = *(const ushort4*)&res[base];
        float rv[4] = {bf2f(r.x), bf2f(r.y), bf2f(r.z), bf2f(r.w)};
        float* vp = &v.x;
        ushort4 u4;
        unsigned short* up = &u4.x;
#pragma unroll
        for (int j = 0; j < 4; ++j) {
            float2 st = *(const float2*)&stats[(b * 128 + c + j) * 2];
            float t = (vp[j] - st.x) * st.y + rv[j];
            t = fmaxf(t, 0.f);
            T[(cq * 4 + j) * 68 + e] = t;
            up[j] = f2bf(t);
        }
        if (eg < E_TOT) *(ushort4*)&x2b[base] = u4;
    }
    __syncthreads();
#pragma unroll
    for (int i = 0; i < 2; ++i) {
        int q = tid + i * 256;
        int cl = q >> 4, eq = q & 15;
        int e4 = e0 + eq * 4;
        int cglob = sect + cg * 32 + cl;
        float4 v = *(const float4*)&T[cl * 68 + eq * 4];
        long obase = ((long)b * 384 + cglob) * E_TOT + e4;
        if (e4 + 3 < E_TOT) {
            *(float4*)&outb[obase] = v;
        } else {
            const float* vp = &v.x;
            for (int j = 0; j < 4; ++j)
                if (e4 + j < E_TOT) outb[obase + j] = vp[j];
        }
    }
}

// ---------------------------------------------------------------------------
// final: s = sigmoid(wA - wB) (bf16 in, edge-major); agg = x2e*s + x2p*(1-s)
// ---------------------------------------------------------------------------
__global__ __launch_bounds__(256)
void final_agg_k(const ushort_t* __restrict__ wab, const ushort_t* __restrict__ wbb,
                 float* __restrict__ outb)
{
    __shared__ float S[32 * 68];
    int b = blockIdx.z, cg = blockIdx.y;
    int e0 = blockIdx.x * 64;
    int tid = threadIdx.x;
#pragma unroll
    for (int i = 0; i < 2; ++i) {
        int q = tid + i * 256;
        int e = q >> 3, cq = q & 7;
        int eg = e0 + e;
        int se = (eg < E_TOT) ? eg : (E_TOT - 1);
        int c = cg * 32 + cq * 4;
        long base = ((long)b * E_TOT + se) * 128 + c;
        ushort4 a4 = *(const ushort4*)&wab[base];
        ushort4 b4 = *(const ushort4*)&wbb[base];
        const unsigned short* ap = &a4.x;
        const unsigned short* bp = &b4.x;
#pragma unroll
        for (int j = 0; j < 4; ++j)
            S[(cq * 4 + j) * 68 + e] = sigmoidf_(bf2f(ap[j]) - bf2f(bp[j]));
    }
    __syncthreads();
#pragma unroll
    for (int i = 0; i < 2; ++i) {
        int q = tid + i * 256;
        int cl = q >> 4, eq = q & 15;
        int e4 = e0 + eq * 4;
        int cglob = cg * 32 + cl;
        float4 s = *(const float4*)&S[cl * 68 + eq * 4];
        long eb = ((long)b * 384 + cglob) * E_TOT + e4;
        long pb = ((long)b * 384 + 128 + cglob) * E_TOT + e4;
        long ab = ((long)b * 384 + 256 + cglob) * E_TOT + e4;
        if (e4 + 3 < E_TOT) {
            float4 xe = *(const float4*)&outb[eb];
            float4 xp = *(const float4*)&outb[pb];
            float* sp = &s.x; float* xep = &xe.x; float* xpp = &xp.x;
            float4 r; float* rp = &r.x;
#pragma unroll
            for (int j = 0; j < 4; ++j)
                rp[j] = xep[j] * sp[j] + xpp[j] * (1.f - sp[j]);
            *(float4*)&outb[ab] = r;
        } else {
            const float* sp = &s.x;
            for (int j = 0; j < 4; ++j) {
                if (e4 + j < E_TOT) {
                    float xe = outb[eb + j], xp = outb[pb + j];
                    outb[ab + j] = xe * sp[j] + xp * (1.f - sp[j]);
                }
            }
        }
    }
}

// ---------------------------------------------------------------------------
extern "C" void kernel_launch(void* const* d_in, const int* in_sizes, int n_in,
                              void* d_out, int out_size, void* d_ws, size_t ws_size,
                              hipStream_t stream)
{
    const float* fe   = (const float*)d_in[0];
    const int*   gemm = (const int*)  d_in[1];
    const float* w_e1 = (const float*)d_in[2];  const float* b_e1 = (const float*)d_in[3];
    const float* w_p1 = (const float*)d_in[4];  const float* b_p1 = (const float*)d_in[5];
    const float* w_e2 = (const float*)d_in[6];  const float* b_e2 = (const float*)d_in[7];
    const float* w_p2 = (const float*)d_in[8];  const float* b_p2 = (const float*)d_in[9];
    const float* wa   = (const float*)d_in[10]; const float* ba   = (const float*)d_in[11];
    const float* wb   = (const float*)d_in[12]; const float* bb   = (const float*)d_in[13];
    const float* wal  = (const float*)d_in[14]; const float* bal  = (const float*)d_in[15];
    const float* wbl  = (const float*)d_in[16]; const float* bbl  = (const float*)d_in[17];
    const float* wat  = (const float*)d_in[18]; const float* bat  = (const float*)d_in[19];
    const float* wbt  = (const float*)d_in[20]; const float* bbt  = (const float*)d_in[21];
    const float* waf  = (const float*)d_in[22]; const float* baf  = (const float*)d_in[23];
    const float* wbf  = (const float*)d_in[24]; const float* bbf  = (const float*)d_in[25];
    float* out = (float*)d_out;

    const long EB = (long)E_TOT;

    // ---- workspace layout (256B-aligned chunks)
    char* wp = (char*)d_ws;
    auto alloc = [&](size_t bytes) -> void* {
        void* r = (void*)wp;
        wp += (bytes + 255) & ~(size_t)255;
        return r;
    };
    float* FET   = (float*)alloc((size_t)B_TOT * EB * 8 * 4);
    float* TMP   = (float*)alloc((size_t)B_TOT * EB * 128 * 4);
    float* XB2   = (float*)alloc((size_t)B_TOT * EB * 128 * 4);
    float* PART  = (float*)alloc((size_t)B_TOT * NBLK * 128 * 2 * 4);
    float* STATS = (float*)alloc((size_t)B_TOT * 128 * 2 * 4);
    ushort_t* X1B   = (ushort_t*)alloc((size_t)B_TOT * EB * 128 * 2);
    ushort_t* X2B   = (ushort_t*)alloc((size_t)B_TOT * EB * 128 * 2);
    ushort_t* XALLB = (ushort_t*)alloc((size_t)B_TOT * EB * 64 * 2);
    ushort_t* WT_E2 = (ushort_t*)alloc(128 * 5 * 128 * 2);
    ushort_t* WT_P2 = (ushort_t*)alloc(128 * 5 * 128 * 2);
    ushort_t* WT_AT = (ushort_t*)alloc(64 * 5 * 64 * 2);
    ushort_t* WT_BT = (ushort_t*)alloc(64 * 5 * 64 * 2);
    ushort_t* WT_A  = (ushort_t*)alloc(32 * 128 * 2);
    ushort_t* WT_B  = (ushort_t*)alloc(32 * 128 * 2);
    ushort_t* WT_AL = (ushort_t*)alloc(64 * 64 * 2);
    ushort_t* WT_BL = (ushort_t*)alloc(64 * 64 * 2);
    ushort_t* WT_AF = (ushort_t*)alloc(128 * 128 * 2);
    ushort_t* WT_BF = (ushort_t*)alloc(128 * 128 * 2);

    if ((size_t)(wp - (char*)d_ws) > ws_size) {
        fprintf(stderr, "kernel_launch: ws too small (%zu < %zu)\n",
                ws_size, (size_t)(wp - (char*)d_ws));
        return;
    }

    // x_a_two lives in out's agg section (free until final_agg)
    float* XA2 = out + 256 * EB;          // element (b,e,c) at XA2[b*384*E + e*128 + c]
    const long XA2_BSTR = 384 * EB;

    dim3 blk(256);
    dim3 gE(NBLK, 1, B_TOT);
    dim3 gT((E_TOT + 255) / 256, 1, B_TOT);
    dim3 gN(NBLK, 4, B_TOT);
    int gA = (int)(((long)B_TOT * EB * 128 / 8 + 255) / 256);

    // ---- prep
    transpose_in_k<<<gT, blk, 0, stream>>>(fe, FET);
    wtrans_mesh_k<128, 128><<<320, blk, 0, stream>>>(w_e2, WT_E2);
    wtrans_mesh_k<128, 128><<<320, blk, 0, stream>>>(w_p2, WT_P2);
    wtrans_mesh_k<64, 64><<<80, blk, 0, stream>>>(wat, WT_AT);
    wtrans_mesh_k<64, 64><<<80, blk, 0, stream>>>(wbt, WT_BT);
    cast_bf16_k<<<16, blk, 0, stream>>>(wa, WT_A, 32 * 128);
    cast_bf16_k<<<16, blk, 0, stream>>>(wb, WT_B, 32 * 128);
    cast_bf16_k<<<16, blk, 0, stream>>>(wal, WT_AL, 64 * 64);
    cast_bf16_k<<<16, blk, 0, stream>>>(wbl, WT_BL, 64 * 64);
    cast_bf16_k<<<64, blk, 0, stream>>>(waf, WT_AF, 128 * 128);
    cast_bf16_k<<<64, blk, 0, stream>>>(wbf, WT_BF, 128 * 128);

    // ---- edge branch
    mesh_conv_k<5, 128, true><<<gE, blk, 0, stream>>>(FET, EB * 8, 8, 0, gemm,
        w_e1, b_e1, TMP, EB * 128, 128, 0, PART);
    stats_fin2_k<<<256, blk, 0, stream>>>(PART, STATS);
    norm_act_k<0><<<gA, blk, 0, stream>>>(TMP, STATS, X1B);             // x1_e (bf16)
    mesh_mfma_k<128, 128, true><<<gE, blk, 0, stream>>>(X1B, EB * 128, gemm,
        WT_E2, b_e2, TMP, EB * 128, 128, 0, PART);
    stats_fin2_k<<<256, blk, 0, stream>>>(PART, STATS);
    norm_res_cm_k<<<gN, blk, 0, stream>>>(TMP, X1B, STATS, out, 0, X2B); // x2_e
    conv1_mfma_k<128, 32, false, true, true><<<gE, blk, 0, stream>>>(X2B, EB * 128,
        WT_A, ba, XALLB, EB * 64, 64, 0, nullptr);                       // x_all[:,0:32]

    // ---- point branch
    mesh_conv_k<3, 128, true><<<gE, blk, 0, stream>>>(FET, EB * 8, 8, 5, gemm,
        w_p1, b_p1, TMP, EB * 128, 128, 0, PART);
    stats_fin2_k<<<256, blk, 0, stream>>>(PART, STATS);
    norm_act_k<0><<<gA, blk, 0, stream>>>(TMP, STATS, X1B);             // x1_p (bf16)
    mesh_mfma_k<128, 128, true><<<gE, blk, 0, stream>>>(X1B, EB * 128, gemm,
        WT_P2, b_p2, TMP, EB * 128, 128, 0, PART);
    stats_fin2_k<<<256, blk, 0, stream>>>(PART, STATS);
    norm_res_cm_k<<<gN, blk, 0, stream>>>(TMP, X1B, STATS, out, 128, X2B); // x2_p
    conv1_mfma_k<128, 32, false, true, true><<<gE, blk, 0, stream>>>(X2B, EB * 128,
        WT_B, bb, XALLB, EB * 64, 64, 32, nullptr);                      // x_all[:,32:64]

    // ---- decoder heads
    conv1_mfma_k<64, 64, false, true, false><<<gE, blk, 0, stream>>>(XALLB, EB * 64,
        WT_AL, bal, XA2, XA2_BSTR, 128, 0, nullptr);
    mesh_mfma_k<64, 64, false><<<gE, blk, 0, stream>>>(XALLB, EB * 64, gemm,
        WT_AT, bat, XA2, XA2_BSTR, 128, 64, nullptr);
    conv1_mfma_k<64, 64, false, true, false><<<gE, blk, 0, stream>>>(XALLB, EB * 64,
        WT_BL, bbl, XB2, EB * 128, 128, 0, nullptr);
    mesh_mfma_k<64, 64, false><<<gE, blk, 0, stream>>>(XALLB, EB * 64, gemm,
        WT_BT, bbt, XB2, EB * 128, 128, 64, nullptr);

    // ---- gates
    conv1_mfma_k<128, 128, true, false, false><<<gE, blk, 0, stream>>>(XA2, XA2_BSTR,
        WT_AF, baf, TMP, EB * 128, 128, 0, PART);
    stats_fin2_k<<<256, blk, 0, stream>>>(PART, STATS);
    norm_act_k<1><<<gA, blk, 0, stream>>>(TMP, STATS, X1B);             // wA (bf16)
    conv1_mfma_k<128, 128, true, false, false><<<gE, blk, 0, stream>>>(XB2, EB * 128,
        WT_BF, bbf, TMP, EB * 128, 128, 0, PART);
    stats_fin2_k<<<256, blk, 0, stream>>>(PART, STATS);
    norm_act_k<1><<<gA, blk, 0, stream>>>(TMP, STATS, X2B);             // wB (bf16)

    // ---- aggregate
    final_agg_k<<<gN, blk, 0, stream>>>(X1B, X2B, out);
}

// Round 4
// 403.050 us; speedup vs baseline: 3.5863x; 1.2226x over previous
//
#include <hip/hip_runtime.h>
#include <cstdio>
#include <math.h>

// ---------------------------------------------------------------------------
// MeshEncoderDecoder — round 4: f16 activations everywhere, packed-f16 staging
// math, MFMA layer-1, fused gate+aggregate, merged weight prep.
// ---------------------------------------------------------------------------

#define E_TOT 50000
#define B_TOT 2
#define TILE_E 64
#define NBLK ((E_TOT + TILE_E - 1) / TILE_E)   // 782

typedef _Float16 half_t;
typedef __attribute__((ext_vector_type(2))) _Float16 h2;
typedef __attribute__((ext_vector_type(4))) _Float16 h4;
typedef __attribute__((ext_vector_type(8))) _Float16 h8;
typedef __attribute__((ext_vector_type(4))) float f32x4;

__device__ __forceinline__ float sigmoidf_(float x) {
    return 1.0f / (1.0f + __expf(-x));
}
__device__ __forceinline__ h8 habs8(h8 x) {
    union { h8 h; unsigned int u[4]; } v;
    v.h = x;
#pragma unroll
    for (int i = 0; i < 4; ++i) v.u[i] &= 0x7FFF7FFFu;
    return v.h;
}

// ---------------------------------------------------------------------------
// weight arena offsets (halves)
// ---------------------------------------------------------------------------
#define OFF_WT1E  0          // 128*32
#define OFF_WT1P  4096       // 128*32
#define OFF_WTE2  8192       // 128*640
#define OFF_WTP2  90112      // 128*640
#define OFF_WTAT  172032     // 64*320
#define OFF_WTBT  192512     // 64*320
#define OFF_WTA   212992     // 32*128
#define OFF_WTB   217088     // 32*128
#define OFF_WTAL  221184     // 64*64
#define OFF_WTBL  225280     // 64*64
#define OFF_WTAF  229376     // 128*128
#define OFF_WTBF  245760     // 128*128
#define WARENA_N  262144

// one launch converts/reorders all weights to f16
__global__ __launch_bounds__(256)
void wprep_k(half_t* __restrict__ wa_,
             const float* __restrict__ w_e1, const float* __restrict__ w_p1,
             const float* __restrict__ w_e2, const float* __restrict__ w_p2,
             const float* __restrict__ wat,  const float* __restrict__ wbt,
             const float* __restrict__ wa,   const float* __restrict__ wb,
             const float* __restrict__ wal,  const float* __restrict__ wbl,
             const float* __restrict__ waf,  const float* __restrict__ wbf)
{
    int idx = blockIdx.x * 256 + threadIdx.x;
    switch (blockIdx.y) {
    case 0: if (idx < 4096) { int o = idx >> 5, k = idx & 31; float v = 0.f;
            if (k < 25) { int s = k / 5, c = k % 5; v = w_e1[o * 25 + c * 5 + s]; }
            wa_[OFF_WT1E + idx] = (half_t)v; } break;
    case 1: if (idx < 4096) { int o = idx >> 5, k = idx & 31; float v = 0.f;
            if (k < 15) { int s = k / 3, c = k % 3; v = w_p1[o * 15 + c * 5 + s]; }
            wa_[OFF_WT1P + idx] = (half_t)v; } break;
    case 2: if (idx < 81920) { int o = idx / 640, r = idx % 640, s = r >> 7, c = r & 127;
            wa_[OFF_WTE2 + idx] = (half_t)w_e2[(o * 128 + c) * 5 + s]; } break;
    case 3: if (idx < 81920) { int o = idx / 640, r = idx % 640, s = r >> 7, c = r & 127;
            wa_[OFF_WTP2 + idx] = (half_t)w_p2[(o * 128 + c) * 5 + s]; } break;
    case 4: if (idx < 20480) { int o = idx / 320, r = idx % 320, s = r >> 6, c = r & 63;
            wa_[OFF_WTAT + idx] = (half_t)wat[(o * 64 + c) * 5 + s]; } break;
    case 5: if (idx < 20480) { int o = idx / 320, r = idx % 320, s = r >> 6, c = r & 63;
            wa_[OFF_WTBT + idx] = (half_t)wbt[(o * 64 + c) * 5 + s]; } break;
    case 6: if (idx < 4096)  wa_[OFF_WTA  + idx] = (half_t)wa[idx];  break;
    case 7: if (idx < 4096)  wa_[OFF_WTB  + idx] = (half_t)wb[idx];  break;
    case 8: if (idx < 4096)  wa_[OFF_WTAL + idx] = (half_t)wal[idx]; break;
    case 9: if (idx < 4096)  wa_[OFF_WTBL + idx] = (half_t)wbl[idx]; break;
    case 10: if (idx < 16384) wa_[OFF_WTAF + idx] = (half_t)waf[idx]; break;
    case 11: if (idx < 16384) wa_[OFF_WTBF + idx] = (half_t)wbf[idx]; break;
    }
}

// ---------------------------------------------------------------------------
// transpose fe (b, 8, E) -> fe_t (b, E, 8) f32
// ---------------------------------------------------------------------------
__global__ __launch_bounds__(256)
void transpose_in_k(const float* __restrict__ fe, float* __restrict__ fet)
{
    int b = blockIdx.z;
    int e = blockIdx.x * 256 + threadIdx.x;
    if (e >= E_TOT) return;
    float v[8];
#pragma unroll
    for (int c = 0; c < 8; ++c)
        v[c] = fe[((long)b * 8 + c) * E_TOT + e];
    float4* dst = (float4*)&fet[((long)b * E_TOT + e) * 8];
    dst[0] = make_float4(v[0], v[1], v[2], v[3]);
    dst[1] = make_float4(v[4], v[5], v[6], v[7]);
}

// ---------------------------------------------------------------------------
// layer-1 mesh conv via MFMA: CIN channels (at offset C0 of 8), K=5*CIN pad 32.
// FET f32 edge-major [b][E][8] -> y f16 [b][E][128] + stats partials (O=128).
// ---------------------------------------------------------------------------
template<int CIN, int C0>
__global__ __launch_bounds__(256)
void mesh1_mfma_k(const float* __restrict__ fet, const int* __restrict__ gemm,
                  const half_t* __restrict__ wt1, const float* __restrict__ bias,
                  half_t* __restrict__ y, float* __restrict__ part)
{
    __shared__ half_t Gl[64 * 40];
    __shared__ int nidx[64][4];

    const int tid  = threadIdx.x;
    const int b    = blockIdx.z;
    const int e0   = blockIdx.x * TILE_E;
    const int lane = tid & 63;
    const int wv   = tid >> 6;
    const int l15  = lane & 15;
    const int kg   = lane >> 4;
    const int o0   = wv * 32;

    const float* xb = fet + (long)b * E_TOT * 8;
    half_t*      yb = y   + (long)b * E_TOT * 128;

    {
        int e = tid >> 2, s = tid & 3;
        int eg = e0 + e;
        nidx[e][s] = (eg < E_TOT) ? gemm[((long)b * E_TOT + eg) * 4 + s] : 0;
    }
    __syncthreads();

    {
        int e = tid >> 2, q = tid & 3;
        int eg = e0 + e;
        int se = (eg < E_TOT) ? eg : 0;
        if (q == 0) {
            float4 r0 = *(const float4*)&xb[(long)se * 8];
            float4 r1 = *(const float4*)&xb[(long)se * 8 + 4];
            float rr[8] = {r0.x, r0.y, r0.z, r0.w, r1.x, r1.y, r1.z, r1.w};
#pragma unroll
            for (int c = 0; c < CIN; ++c) Gl[e * 40 + c] = (half_t)rr[C0 + c];
#pragma unroll
            for (int k = 5 * CIN; k < 32; ++k) Gl[e * 40 + k] = (half_t)0.f;
        } else if (q <= 2) {
            int ia = q - 1, ib = q + 1;      // q=1: (f1,f3); q=2: (f2,f4)
            const float* pa = &xb[(long)nidx[e][ia] * 8];
            const float* pb = &xb[(long)nidx[e][ib] * 8];
            float4 a0 = *(const float4*)pa, a1 = *(const float4*)(pa + 4);
            float4 b0 = *(const float4*)pb, b1 = *(const float4*)(pb + 4);
            float aa[8] = {a0.x, a0.y, a0.z, a0.w, a1.x, a1.y, a1.z, a1.w};
            float bb8[8] = {b0.x, b0.y, b0.z, b0.w, b1.x, b1.y, b1.z, b1.w};
            int ks1 = q * CIN;               // s1 / s2
            int ks2 = (q + 2) * CIN;         // s3 / s4
#pragma unroll
            for (int c = 0; c < CIN; ++c) {
                float av = aa[C0 + c], bv = bb8[C0 + c];
                Gl[e * 40 + ks1 + c] = (half_t)(av + bv);
                Gl[e * 40 + ks2 + c] = (half_t)fabsf(av - bv);
            }
        }
    }
    __syncthreads();

    f32x4 acc[4][2];
#pragma unroll
    for (int mt = 0; mt < 4; ++mt)
#pragma unroll
        for (int nt = 0; nt < 2; ++nt)
#pragma unroll
            for (int j = 0; j < 4; ++j) acc[mt][nt][j] = 0.f;

    h8 bw[2];
#pragma unroll
    for (int nt = 0; nt < 2; ++nt)
        bw[nt] = *(const h8*)(wt1 + (long)(o0 + nt * 16 + l15) * 32 + kg * 8);
#pragma unroll
    for (int mt = 0; mt < 4; ++mt) {
        int row = mt * 16 + l15;
        h8 a = *(const h8*)(&Gl[row * 40 + kg * 8]);
#pragma unroll
        for (int nt = 0; nt < 2; ++nt)
            acc[mt][nt] = __builtin_amdgcn_mfma_f32_16x16x32_f16(a, bw[nt], acc[mt][nt], 0, 0, 0);
    }

    float bv[2], s1[2], s2[2];
#pragma unroll
    for (int nt = 0; nt < 2; ++nt) {
        bv[nt] = bias[o0 + nt * 16 + l15];
        s1[nt] = 0.f; s2[nt] = 0.f;
    }
#pragma unroll
    for (int mt = 0; mt < 4; ++mt) {
        int ebase = e0 + mt * 16 + (kg << 2);
#pragma unroll
        for (int j = 0; j < 4; ++j) {
            if (ebase + j < E_TOT) {
#pragma unroll
                for (int nt = 0; nt < 2; ++nt) {
                    float v = acc[mt][nt][j] + bv[nt];
                    yb[(long)(ebase + j) * 128 + o0 + nt * 16 + l15] = (half_t)v;
                    s1[nt] += v; s2[nt] += v * v;
                }
            }
        }
    }
#pragma unroll
    for (int nt = 0; nt < 2; ++nt) {
        s1[nt] += __shfl_xor(s1[nt], 16); s1[nt] += __shfl_xor(s1[nt], 32);
        s2[nt] += __shfl_xor(s2[nt], 16); s2[nt] += __shfl_xor(s2[nt], 32);
    }
    if (lane < 16) {
        long pb = ((long)b * NBLK + blockIdx.x) * 128;
#pragma unroll
        for (int nt = 0; nt < 2; ++nt) {
            part[(pb + o0 + nt * 16 + lane) * 2 + 0] = s1[nt];
            part[(pb + o0 + nt * 16 + lane) * 2 + 1] = s2[nt];
        }
    }
}

// ---------------------------------------------------------------------------
// MFMA mesh conv (f16): x f16 edge-major [b][E][C], wt f16 [(o*5+s)*C+c],
// y f16 edge-major [b][E][outS] at col oOff. Optional stats (O assumed 128).
// ---------------------------------------------------------------------------
template<int C, int O, bool STATS>
__global__ __launch_bounds__(256)
void mesh_mfma_k(const half_t* __restrict__ x, long xbstr,
                 const int* __restrict__ gemm,
                 const half_t* __restrict__ wt, const float* __restrict__ bias,
                 half_t* __restrict__ y, long ybstr, int outS, int oOff,
                 float* __restrict__ part)
{
    constexpr int SL = C / 8;
    constexpr int NT = O / 64;
    constexpr int KS = C / 32;
    constexpr int T  = (64 * SL) / 256;

    __shared__ h8 GlA[64 * SL];
    __shared__ h8 GlB[64 * SL];
    __shared__ int nidx[64][4];

    const int tid  = threadIdx.x;
    const int b    = blockIdx.z;
    const int e0   = blockIdx.x * TILE_E;
    const int lane = tid & 63;
    const int wv   = tid >> 6;
    const int l15  = lane & 15;
    const int kg   = lane >> 4;
    const int o0   = wv * (O / 4);

    const half_t* xb = x + (long)b * xbstr;
    half_t*       yb = y + (long)b * ybstr;

    {
        int e = tid >> 2, s = tid & 3;
        int eg = e0 + e;
        nidx[e][s] = (eg < E_TOT) ? gemm[((long)b * E_TOT + eg) * 4 + s] : 0;
    }

    auto stage_self = [&](h8* dst) {
#pragma unroll
        for (int t = 0; t < T; ++t) {
            int q = t * 256 + tid;
            int e = q / SL, c8 = q % SL;
            int eg = e0 + e;
            int se = (eg < E_TOT) ? eg : 0;
            dst[(e * SL + c8) ^ (e & 7)] = *(const h8*)(xb + (long)se * C + c8 * 8);
        }
    };
    auto stage_pair = [&](h8* dstS, h8* dstD, int ia, int ib) {
#pragma unroll
        for (int t = 0; t < T; ++t) {
            int q = t * 256 + tid;
            int e = q / SL, c8 = q % SL;
            int na = nidx[e][ia], nb = nidx[e][ib];
            h8 a  = *(const h8*)(xb + (long)na * C + c8 * 8);
            h8 bq = *(const h8*)(xb + (long)nb * C + c8 * 8);
            int slot = (e * SL + c8) ^ (e & 7);
            dstS[slot] = a + bq;
            dstD[slot] = habs8(a - bq);
        }
    };

    f32x4 acc[4][NT];
#pragma unroll
    for (int mt = 0; mt < 4; ++mt)
#pragma unroll
        for (int nt = 0; nt < NT; ++nt)
#pragma unroll
            for (int j = 0; j < 4; ++j) acc[mt][nt][j] = 0.f;

    auto compute_chunk = [&](const h8* buf, int s) {
#pragma unroll
        for (int ks = 0; ks < KS; ++ks) {
            h8 bw[NT];
#pragma unroll
            for (int nt = 0; nt < NT; ++nt)
                bw[nt] = *(const h8*)(wt + ((long)(o0 + nt * 16 + l15) * 5 + s) * C + ks * 32 + kg * 8);
#pragma unroll
            for (int mt = 0; mt < 4; ++mt) {
                int row = mt * 16 + l15;
                h8 a = buf[row * SL + ((ks * 4 + kg) ^ (l15 & 7))];
#pragma unroll
                for (int nt = 0; nt < NT; ++nt)
                    acc[mt][nt] = __builtin_amdgcn_mfma_f32_16x16x32_f16(a, bw[nt], acc[mt][nt], 0, 0, 0);
            }
        }
    };

    stage_self(GlA);
    __syncthreads();
    compute_chunk(GlA, 0);
    __syncthreads();
    stage_pair(GlA, GlB, 0, 2);   // s1=f1+f3, s3=|f1-f3|
    __syncthreads();
    compute_chunk(GlA, 1);
    compute_chunk(GlB, 3);
    __syncthreads();
    stage_pair(GlA, GlB, 1, 3);   // s2=f2+f4, s4=|f2-f4|
    __syncthreads();
    compute_chunk(GlA, 2);
    compute_chunk(GlB, 4);

    float bv[NT], s1[NT], s2[NT];
#pragma unroll
    for (int nt = 0; nt < NT; ++nt) {
        bv[nt] = bias[o0 + nt * 16 + l15];
        s1[nt] = 0.f; s2[nt] = 0.f;
    }
#pragma unroll
    for (int mt = 0; mt < 4; ++mt) {
        int ebase = e0 + mt * 16 + (kg << 2);
#pragma unroll
        for (int j = 0; j < 4; ++j) {
            if (ebase + j < E_TOT) {
#pragma unroll
                for (int nt = 0; nt < NT; ++nt) {
                    float v = acc[mt][nt][j] + bv[nt];
                    yb[(long)(ebase + j) * outS + oOff + o0 + nt * 16 + l15] = (half_t)v;
                    if constexpr (STATS) { s1[nt] += v; s2[nt] += v * v; }
                }
            }
        }
    }
    if constexpr (STATS) {
#pragma unroll
        for (int nt = 0; nt < NT; ++nt) {
            s1[nt] += __shfl_xor(s1[nt], 16); s1[nt] += __shfl_xor(s1[nt], 32);
            s2[nt] += __shfl_xor(s2[nt], 16); s2[nt] += __shfl_xor(s2[nt], 32);
        }
        if (lane < 16) {
            long pb = ((long)b * NBLK + blockIdx.x) * O;
#pragma unroll
            for (int nt = 0; nt < NT; ++nt) {
                part[(pb + o0 + nt * 16 + lane) * 2 + 0] = s1[nt];
                part[(pb + o0 + nt * 16 + lane) * 2 + 1] = s2[nt];
            }
        }
    }
}

// ---------------------------------------------------------------------------
// MFMA 1x1 conv (f16 in/out). O>=64: waves split o; O==32: waves split edges.
// ---------------------------------------------------------------------------
template<int C, int O, bool STATS>
__global__ __launch_bounds__(256)
void conv1_mfma_k(const half_t* __restrict__ x, long xbstr,
                  const half_t* __restrict__ wt, const float* __restrict__ bias,
                  half_t* __restrict__ y, long ybstr, int outS, int oOff,
                  float* __restrict__ part)
{
    constexpr int SL = C / 8;
    constexpr int KS = C / 32;
    constexpr int T  = (64 * SL) / 256;
    constexpr int NT = (O >= 64) ? (O / 64) : 2;
    constexpr int MT = (O >= 64) ? 4 : 1;

    __shared__ h8 Gl[64 * SL];

    const int tid  = threadIdx.x;
    const int b    = blockIdx.z;
    const int e0   = blockIdx.x * TILE_E;
    const int lane = tid & 63;
    const int wv   = tid >> 6;
    const int l15  = lane & 15;
    const int kg   = lane >> 4;
    const int o0   = (O >= 64) ? wv * (O / 4) : 0;
    const int eoff = (O >= 64) ? 0 : wv * 16;

    const half_t* xb = x + (long)b * xbstr;
#pragma unroll
    for (int t = 0; t < T; ++t) {
        int q = t * 256 + tid;
        int e = q / SL, c8 = q % SL;
        int eg = e0 + e;
        int se = (eg < E_TOT) ? eg : 0;
        Gl[(e * SL + c8) ^ (e & 7)] = *(const h8*)(xb + (long)se * C + c8 * 8);
    }
    __syncthreads();

    f32x4 acc[MT][NT];
#pragma unroll
    for (int mt = 0; mt < MT; ++mt)
#pragma unroll
        for (int nt = 0; nt < NT; ++nt)
#pragma unroll
            for (int j = 0; j < 4; ++j) acc[mt][nt][j] = 0.f;

#pragma unroll
    for (int ks = 0; ks < KS; ++ks) {
        h8 bw[NT];
#pragma unroll
        for (int nt = 0; nt < NT; ++nt)
            bw[nt] = *(const h8*)(wt + (long)(o0 + nt * 16 + l15) * C + ks * 32 + kg * 8);
#pragma unroll
        for (int mt = 0; mt < MT; ++mt) {
            int row = eoff + mt * 16 + l15;
            h8 a = Gl[row * SL + ((ks * 4 + kg) ^ (row & 7))];
#pragma unroll
            for (int nt = 0; nt < NT; ++nt)
                acc[mt][nt] = __builtin_amdgcn_mfma_f32_16x16x32_f16(a, bw[nt], acc[mt][nt], 0, 0, 0);
        }
    }

    half_t* yb = y + (long)b * ybstr;
    float bv[NT], s1[NT], s2[NT];
#pragma unroll
    for (int nt = 0; nt < NT; ++nt) {
        bv[nt] = bias[o0 + nt * 16 + l15];
        s1[nt] = 0.f; s2[nt] = 0.f;
    }
#pragma unroll
    for (int mt = 0; mt < MT; ++mt) {
        int ebase = e0 + eoff + mt * 16 + (kg << 2);
#pragma unroll
        for (int j = 0; j < 4; ++j) {
            if (ebase + j < E_TOT) {
#pragma unroll
                for (int nt = 0; nt < NT; ++nt) {
                    float v = acc[mt][nt][j] + bv[nt];
                    yb[(long)(ebase + j) * outS + oOff + o0 + nt * 16 + l15] = (half_t)v;
                    if constexpr (STATS) { s1[nt] += v; s2[nt] += v * v; }
                }
            }
        }
    }
    if constexpr (STATS) {
#pragma unroll
        for (int nt = 0; nt < NT; ++nt) {
            s1[nt] += __shfl_xor(s1[nt], 16); s1[nt] += __shfl_xor(s1[nt], 32);
            s2[nt] += __shfl_xor(s2[nt], 16); s2[nt] += __shfl_xor(s2[nt], 32);
        }
        if (lane < 16) {
            long pb = ((long)b * NBLK + blockIdx.x) * O;
#pragma unroll
            for (int nt = 0; nt < NT; ++nt) {
                part[(pb + o0 + nt * 16 + lane) * 2 + 0] = s1[nt];
                part[(pb + o0 + nt * 16 + lane) * 2 + 1] = s2[nt];
            }
        }
    }
}

// ---------------------------------------------------------------------------
// parallel stats finalize: one block per (b,o), O=128
// ---------------------------------------------------------------------------
__global__ __launch_bounds__(256)
void stats_fin2_k(const float* __restrict__ part, float* __restrict__ stats)
{
    int b = blockIdx.x >> 7, o = blockIdx.x & 127;
    int tid = threadIdx.x;
    float s1 = 0.f, s2 = 0.f;
    for (int k = tid; k < NBLK; k += 256) {
        long base = (((long)b * NBLK + k) * 128 + o) * 2;
        s1 += part[base];
        s2 += part[base + 1];
    }
#pragma unroll
    for (int d = 1; d < 64; d <<= 1) {
        s1 += __shfl_xor(s1, d);
        s2 += __shfl_xor(s2, d);
    }
    __shared__ float r1[4], r2[4];
    int wv = tid >> 6;
    if ((tid & 63) == 0) { r1[wv] = s1; r2[wv] = s2; }
    __syncthreads();
    if (tid == 0) {
        s1 = r1[0] + r1[1] + r1[2] + r1[3];
        s2 = r2[0] + r2[1] + r2[2] + r2[3];
        float mean = s1 / (float)E_TOT;
        float var  = s2 / (float)E_TOT - mean * mean;
        var = fmaxf(var, 0.f);
        stats[(b * 128 + o) * 2 + 0] = mean;
        stats[(b * 128 + o) * 2 + 1] = rsqrtf(var + 1e-5f);
    }
}

// ---------------------------------------------------------------------------
// x1 = relu(inorm(tmp)): f16 -> f16 edge-major
// ---------------------------------------------------------------------------
__global__ __launch_bounds__(256)
void norm_act_k(const half_t* __restrict__ xin, const float* __restrict__ stats,
                half_t* __restrict__ yout)
{
    long q = (long)blockIdx.x * 256 + threadIdx.x;
    long tot = (long)B_TOT * E_TOT * 128 / 8;
    if (q >= tot) return;
    long idx = q * 8;
    int c = (int)(idx & 127);
    int b = (int)((idx >> 7) / E_TOT);
    h8 v = *(const h8*)&xin[idx];
    h8 r;
#pragma unroll
    for (int j = 0; j < 8; ++j) {
        float2 st = *(const float2*)&stats[(b * 128 + c + j) * 2];
        float t = ((float)v[j] - st.x) * st.y;
        r[j] = (half_t)fmaxf(t, 0.f);
    }
    *(h8*)&yout[idx] = r;
}

// ---------------------------------------------------------------------------
// x2 = relu(inorm(tmp) + res): f32 channel-major into out section + f16 copy
// ---------------------------------------------------------------------------
__global__ __launch_bounds__(256)
void norm_res_cm_k(const half_t* __restrict__ xin, const half_t* __restrict__ res,
                   const float* __restrict__ stats, float* __restrict__ outb, int sect,
                   half_t* __restrict__ x2b)
{
    __shared__ float T[32 * 68];
    int b = blockIdx.z, cg = blockIdx.y;
    int e0 = blockIdx.x * 64;
    int tid = threadIdx.x;
#pragma unroll
    for (int i = 0; i < 2; ++i) {
        int q = tid + i * 256;
        int e = q >> 3, cq = q & 7;
        int eg = e0 + e;
        int se = (eg < E_TOT) ? eg : (E_TOT - 1);
        int c = cg * 32 + cq * 4;
        long base = ((long)b * E_TOT + se) * 128 + c;
        h4 v4 = *(const h4*)&xin[base];
        h4 r4 = *(const h4*)&res[base];
        h4 o4;
#pragma unroll
        for (int j = 0; j < 4; ++j) {
            float2 st = *(const float2*)&stats[(b * 128 + c + j) * 2];
            float t = ((float)v4[j] - st.x) * st.y + (float)r4[j];
            t = fmaxf(t, 0.f);
            T[(cq * 4 + j) * 68 + e] = t;
            o4[j] = (half_t)t;
        }
        if (eg < E_TOT) *(h4*)&x2b[base] = o4;
    }
    __syncthreads();
#pragma unroll
    for (int i = 0; i < 2; ++i) {
        int q = tid + i * 256;
        int cl = q >> 4, eq = q & 15;
        int e4 = e0 + eq * 4;
        int cglob = sect + cg * 32 + cl;
        float4 v = *(const float4*)&T[cl * 68 + eq * 4];
        long obase = ((long)b * 384 + cglob) * E_TOT + e4;
        if (e4 + 3 < E_TOT) {
            *(float4*)&outb[obase] = v;
        } else {
            const float* vp = &v.x;
            for (int j = 0; j < 4; ++j)
                if (e4 + j < E_TOT) outb[obase + j] = vp[j];
        }
    }
}

// ---------------------------------------------------------------------------
// fused gates + aggregate: s = sigmoid(sigmoid(inormA) - sigmoid(inormB));
// agg = x2e*s + x2p*(1-s); reads tA/tB f16 edge-major + out e/p sections
// ---------------------------------------------------------------------------
__global__ __launch_bounds__(256)
void gate_agg_k(const half_t* __restrict__ tA, const half_t* __restrict__ tB,
                const float* __restrict__ statsA, const float* __restrict__ statsB,
                float* __restrict__ outb)
{
    __shared__ float S[32 * 68];
    int b = blockIdx.z, cg = blockIdx.y;
    int e0 = blockIdx.x * 64;
    int tid = threadIdx.x;
#pragma unroll
    for (int i = 0; i < 2; ++i) {
        int q = tid + i * 256;
        int e = q >> 3, cq = q & 7;
        int eg = e0 + e;
        int se = (eg < E_TOT) ? eg : (E_TOT - 1);
        int c = cg * 32 + cq * 4;
        long base = ((long)b * E_TOT + se) * 128 + c;
        h4 a4 = *(const h4*)&tA[base];
        h4 b4 = *(const h4*)&tB[base];
#pragma unroll
        for (int j = 0; j < 4; ++j) {
            float2 sa = *(const float2*)&statsA[(b * 128 + c + j) * 2];
            float2 sb = *(const float2*)&statsB[(b * 128 + c + j) * 2];
            float na = sigmoidf_(((float)a4[j] - sa.x) * sa.y);
            float nb = sigmoidf_(((float)b4[j] - sb.x) * sb.y);
            S[(cq * 4 + j) * 68 + e] = sigmoidf_(na - nb);
        }
    }
    __syncthreads();
#pragma unroll
    for (int i = 0; i < 2; ++i) {
        int q = tid + i * 256;
        int cl = q >> 4, eq = q & 15;
        int e4 = e0 + eq * 4;
        int cglob = cg * 32 + cl;
        float4 s = *(const float4*)&S[cl * 68 + eq * 4];
        long eb = ((long)b * 384 + cglob) * E_TOT + e4;
        long pb = ((long)b * 384 + 128 + cglob) * E_TOT + e4;
        long ab = ((long)b * 384 + 256 + cglob) * E_TOT + e4;
        if (e4 + 3 < E_TOT) {
            float4 xe = *(const float4*)&outb[eb];
            float4 xp = *(const float4*)&outb[pb];
            float* sp = &s.x; float* xep = &xe.x; float* xpp = &xp.x;
            float4 r; float* rp = &r.x;
#pragma unroll
            for (int j = 0; j < 4; ++j)
                rp[j] = xep[j] * sp[j] + xpp[j] * (1.f - sp[j]);
            *(float4*)&outb[ab] = r;
        } else {
            const float* sp = &s.x;
            for (int j = 0; j < 4; ++j) {
                if (e4 + j < E_TOT) {
                    float xe = outb[eb + j], xp = outb[pb + j];
                    outb[ab + j] = xe * sp[j] + xp * (1.f - sp[j]);
                }
            }
        }
    }
}

// ---------------------------------------------------------------------------
extern "C" void kernel_launch(void* const* d_in, const int* in_sizes, int n_in,
                              void* d_out, int out_size, void* d_ws, size_t ws_size,
                              hipStream_t stream)
{
    const float* fe   = (const float*)d_in[0];
    const int*   gemm = (const int*)  d_in[1];
    const float* w_e1 = (const float*)d_in[2];  const float* b_e1 = (const float*)d_in[3];
    const float* w_p1 = (const float*)d_in[4];  const float* b_p1 = (const float*)d_in[5];
    const float* w_e2 = (const float*)d_in[6];  const float* b_e2 = (const float*)d_in[7];
    const float* w_p2 = (const float*)d_in[8];  const float* b_p2 = (const float*)d_in[9];
    const float* wa   = (const float*)d_in[10]; const float* ba   = (const float*)d_in[11];
    const float* wb   = (const float*)d_in[12]; const float* bb   = (const float*)d_in[13];
    const float* wal  = (const float*)d_in[14]; const float* bal  = (const float*)d_in[15];
    const float* wbl  = (const float*)d_in[16]; const float* bbl  = (const float*)d_in[17];
    const float* wat  = (const float*)d_in[18]; const float* bat  = (const float*)d_in[19];
    const float* wbt  = (const float*)d_in[20]; const float* bbt  = (const float*)d_in[21];
    const float* waf  = (const float*)d_in[22]; const float* baf  = (const float*)d_in[23];
    const float* wbf  = (const float*)d_in[24]; const float* bbf  = (const float*)d_in[25];
    float* out = (float*)d_out;

    const long EB = (long)E_TOT;

    char* wp = (char*)d_ws;
    auto alloc = [&](size_t bytes) -> void* {
        void* r = (void*)wp;
        wp += (bytes + 255) & ~(size_t)255;
        return r;
    };
    float*  FET    = (float*)alloc((size_t)B_TOT * EB * 8 * 4);
    half_t* TMP    = (half_t*)alloc((size_t)B_TOT * EB * 128 * 2);   // pre-norm / gateA
    half_t* X1     = (half_t*)alloc((size_t)B_TOT * EB * 128 * 2);   // x1 / gateB
    half_t* X2B    = (half_t*)alloc((size_t)B_TOT * EB * 128 * 2);   // x2 (f16 copy)
    half_t* XALL   = (half_t*)alloc((size_t)B_TOT * EB * 64 * 2);
    half_t* XA2    = (half_t*)alloc((size_t)B_TOT * EB * 128 * 2);   // x_a_two
    half_t* XB2    = (half_t*)alloc((size_t)B_TOT * EB * 128 * 2);   // x_b_two
    float*  PART   = (float*)alloc((size_t)B_TOT * NBLK * 128 * 2 * 4);
    float*  STATSA = (float*)alloc((size_t)B_TOT * 128 * 2 * 4);
    float*  STATSB = (float*)alloc((size_t)B_TOT * 128 * 2 * 4);
    half_t* WAR    = (half_t*)alloc((size_t)WARENA_N * 2);

    if ((size_t)(wp - (char*)d_ws) > ws_size) {
        fprintf(stderr, "kernel_launch: ws too small (%zu < %zu)\n",
                ws_size, (size_t)(wp - (char*)d_ws));
        return;
    }

    dim3 blk(256);
    dim3 gE(NBLK, 1, B_TOT);
    dim3 gT((E_TOT + 255) / 256, 1, B_TOT);
    dim3 gN(NBLK, 4, B_TOT);
    int gA = (int)(((long)B_TOT * EB * 128 / 8 + 255) / 256);

    // ---- prep (2 launches)
    wprep_k<<<dim3(320, 12, 1), blk, 0, stream>>>(WAR,
        w_e1, w_p1, w_e2, w_p2, wat, wbt, wa, wb, wal, wbl, waf, wbf);
    transpose_in_k<<<gT, blk, 0, stream>>>(fe, FET);

    // ---- edge branch
    mesh1_mfma_k<5, 0><<<gE, blk, 0, stream>>>(FET, gemm, WAR + OFF_WT1E, b_e1, TMP, PART);
    stats_fin2_k<<<256, blk, 0, stream>>>(PART, STATSA);
    norm_act_k<<<gA, blk, 0, stream>>>(TMP, STATSA, X1);
    mesh_mfma_k<128, 128, true><<<gE, blk, 0, stream>>>(X1, EB * 128, gemm,
        WAR + OFF_WTE2, b_e2, TMP, EB * 128, 128, 0, PART);
    stats_fin2_k<<<256, blk, 0, stream>>>(PART, STATSA);
    norm_res_cm_k<<<gN, blk, 0, stream>>>(TMP, X1, STATSA, out, 0, X2B);
    conv1_mfma_k<128, 32, false><<<gE, blk, 0, stream>>>(X2B, EB * 128,
        WAR + OFF_WTA, ba, XALL, EB * 64, 64, 0, nullptr);

    // ---- point branch
    mesh1_mfma_k<3, 5><<<gE, blk, 0, stream>>>(FET, gemm, WAR + OFF_WT1P, b_p1, TMP, PART);
    stats_fin2_k<<<256, blk, 0, stream>>>(PART, STATSA);
    norm_act_k<<<gA, blk, 0, stream>>>(TMP, STATSA, X1);
    mesh_mfma_k<128, 128, true><<<gE, blk, 0, stream>>>(X1, EB * 128, gemm,
        WAR + OFF_WTP2, b_p2, TMP, EB * 128, 128, 0, PART);
    stats_fin2_k<<<256, blk, 0, stream>>>(PART, STATSA);
    norm_res_cm_k<<<gN, blk, 0, stream>>>(TMP, X1, STATSA, out, 128, X2B);
    conv1_mfma_k<128, 32, false><<<gE, blk, 0, stream>>>(X2B, EB * 128,
        WAR + OFF_WTB, bb, XALL, EB * 64, 64, 32, nullptr);

    // ---- decoder heads
    conv1_mfma_k<64, 64, false><<<gE, blk, 0, stream>>>(XALL, EB * 64,
        WAR + OFF_WTAL, bal, XA2, EB * 128, 128, 0, nullptr);
    mesh_mfma_k<64, 64, false><<<gE, blk, 0, stream>>>(XALL, EB * 64, gemm,
        WAR + OFF_WTAT, bat, XA2, EB * 128, 128, 64, nullptr);
    conv1_mfma_k<64, 64, false><<<gE, blk, 0, stream>>>(XALL, EB * 64,
        WAR + OFF_WTBL, bbl, XB2, EB * 128, 128, 0, nullptr);
    mesh_mfma_k<64, 64, false><<<gE, blk, 0, stream>>>(XALL, EB * 64, gemm,
        WAR + OFF_WTBT, bbt, XB2, EB * 128, 128, 64, nullptr);

    // ---- gates + aggregate
    conv1_mfma_k<128, 128, true><<<gE, blk, 0, stream>>>(XA2, EB * 128,
        WAR + OFF_WTAF, baf, TMP, EB * 128, 128, 0, PART);
    stats_fin2_k<<<256, blk, 0, stream>>>(PART, STATSA);
    conv1_mfma_k<128, 128, true><<<gE, blk, 0, stream>>>(XB2, EB * 128,
        WAR + OFF_WTBF, bbf, X1, EB * 128, 128, 0, PART);
    stats_fin2_k<<<256, blk, 0, stream>>>(PART, STATSB);
    gate_agg_k<<<gN, blk, 0, stream>>>(TMP, X1, STATSA, STATSB, out);
}

// Round 5
// 363.089 us; speedup vs baseline: 3.9810x; 1.1101x over previous
//
#include <hip/hip_runtime.h>
#include <cstdio>
#include <math.h>

// ---------------------------------------------------------------------------
// MeshEncoderDecoder — round 5: 8-wave GEMM blocks, merged branches (13
// launches), fused layer-1 (shared G, K=64), fused heads (linear+mesh in one
// MFMA), gate_agg reads f16 copies.
// ---------------------------------------------------------------------------

#define E_TOT 50000
#define B_TOT 2
#define TILE_E 64
#define NBLK ((E_TOT + TILE_E - 1) / TILE_E)   // 782

typedef _Float16 half_t;
typedef __attribute__((ext_vector_type(4))) _Float16 h4;
typedef __attribute__((ext_vector_type(8))) _Float16 h8;
typedef __attribute__((ext_vector_type(4))) float f32x4;

__device__ __forceinline__ float sigmoidf_(float x) {
    return 1.0f / (1.0f + __expf(-x));
}
__device__ __forceinline__ h8 habs8(h8 x) {
    union { h8 h; unsigned int u[4]; } v;
    v.h = x;
#pragma unroll
    for (int i = 0; i < 4; ++i) v.u[i] &= 0x7FFF7FFFu;
    return v.h;
}

// ---------------------------------------------------------------------------
// weight arena offsets (halves)
// ---------------------------------------------------------------------------
#define OFF_W1E   0          // 128*64 (k = s*8+cc, zero-padded)
#define OFF_W1P   8192       // 128*64
#define OFF_WTE2  16384      // 128*5*128
#define OFF_WTP2  98304      // 128*5*128
#define OFF_WHA   180224     // 128*5*64 (o<64: wal in s0; o>=64: wat)
#define OFF_WHB   221184     // 128*5*64
#define OFF_WTA   262144     // 32*128
#define OFF_WTB   266240     // 32*128
#define OFF_WTAF  270336     // 128*128
#define OFF_WTBF  286720     // 128*128
#define WARENA_N  303104

__global__ __launch_bounds__(256)
void wprep_k(half_t* __restrict__ wa_,
             const float* __restrict__ w_e1, const float* __restrict__ w_p1,
             const float* __restrict__ w_e2, const float* __restrict__ w_p2,
             const float* __restrict__ wat,  const float* __restrict__ wbt,
             const float* __restrict__ wa,   const float* __restrict__ wb,
             const float* __restrict__ wal,  const float* __restrict__ wbl,
             const float* __restrict__ waf,  const float* __restrict__ wbf)
{
    int idx = blockIdx.x * 256 + threadIdx.x;
    switch (blockIdx.y) {
    case 0: if (idx < 8192) { int o = idx >> 6, k = idx & 63, s = k >> 3, cc = k & 7;
            float v = (s < 5 && cc < 5) ? w_e1[o * 25 + cc * 5 + s] : 0.f;
            wa_[OFF_W1E + idx] = (half_t)v; } break;
    case 1: if (idx < 8192) { int o = idx >> 6, k = idx & 63, s = k >> 3, cc = k & 7;
            float v = (s < 5 && cc >= 5) ? w_p1[o * 15 + (cc - 5) * 5 + s] : 0.f;
            wa_[OFF_W1P + idx] = (half_t)v; } break;
    case 2: if (idx < 81920) { int o = idx / 640, r = idx % 640, s = r >> 7, c = r & 127;
            wa_[OFF_WTE2 + idx] = (half_t)w_e2[(o * 128 + c) * 5 + s]; } break;
    case 3: if (idx < 81920) { int o = idx / 640, r = idx % 640, s = r >> 7, c = r & 127;
            wa_[OFF_WTP2 + idx] = (half_t)w_p2[(o * 128 + c) * 5 + s]; } break;
    case 4: if (idx < 40960) { int o = idx / 320, r = idx % 320, s = r >> 6, c = r & 63;
            float v = (o < 64) ? (s == 0 ? wal[o * 64 + c] : 0.f)
                               : wat[((o - 64) * 64 + c) * 5 + s];
            wa_[OFF_WHA + idx] = (half_t)v; } break;
    case 5: if (idx < 40960) { int o = idx / 320, r = idx % 320, s = r >> 6, c = r & 63;
            float v = (o < 64) ? (s == 0 ? wbl[o * 64 + c] : 0.f)
                               : wbt[((o - 64) * 64 + c) * 5 + s];
            wa_[OFF_WHB + idx] = (half_t)v; } break;
    case 6: if (idx < 4096)  wa_[OFF_WTA  + idx] = (half_t)wa[idx];  break;
    case 7: if (idx < 4096)  wa_[OFF_WTB  + idx] = (half_t)wb[idx];  break;
    case 8: if (idx < 16384) wa_[OFF_WTAF + idx] = (half_t)waf[idx]; break;
    case 9: if (idx < 16384) wa_[OFF_WTBF + idx] = (half_t)wbf[idx]; break;
    }
}

// ---------------------------------------------------------------------------
// transpose fe (b, 8, E) -> fe_t (b, E, 8) f32
// ---------------------------------------------------------------------------
__global__ __launch_bounds__(256)
void transpose_in_k(const float* __restrict__ fe, float* __restrict__ fet)
{
    int b = blockIdx.z;
    int e = blockIdx.x * 256 + threadIdx.x;
    if (e >= E_TOT) return;
    float v[8];
#pragma unroll
    for (int c = 0; c < 8; ++c)
        v[c] = fe[((long)b * 8 + c) * E_TOT + e];
    float4* dst = (float4*)&fet[((long)b * E_TOT + e) * 8];
    dst[0] = make_float4(v[0], v[1], v[2], v[3]);
    dst[1] = make_float4(v[4], v[5], v[6], v[7]);
}

// ---------------------------------------------------------------------------
// layer-1 both branches: one staged G (64 edges x K=64: k=s*8+cc, zeros >=40),
// 8 waves: waves 0-3 edge-branch (o-slices of 32), 4-7 point-branch.
// Outputs TMP_E / TMP_P f16 [b][E][128] + stats partials.
// ---------------------------------------------------------------------------
__global__ __launch_bounds__(512)
void mesh1_both_k(const float* __restrict__ fet, const int* __restrict__ gemm,
                  const half_t* __restrict__ war,
                  const float* __restrict__ be1, const float* __restrict__ bp1,
                  half_t* __restrict__ tmpe, half_t* __restrict__ tmpp,
                  float* __restrict__ parte, float* __restrict__ partp)
{
    __shared__ h8 Gl[64 * 8];
    __shared__ int nidx[64][4];

    const int tid  = threadIdx.x;
    const int b    = blockIdx.y;
    const int e0   = blockIdx.x * TILE_E;
    const int lane = tid & 63;
    const int wv   = tid >> 6;         // 0..7
    const int l15  = lane & 15;
    const int kg   = lane >> 4;
    const int br   = wv >> 2;          // 0=edge 1=point
    const int o0   = (wv & 3) * 32;

    const float* xb = fet + (long)b * E_TOT * 8;

    if (tid < 256) {
        int e = tid >> 2, s = tid & 3;
        int eg = e0 + e;
        nidx[e][s] = (eg < E_TOT) ? gemm[((long)b * E_TOT + eg) * 4 + s] : 0;
    }
    __syncthreads();

    {
        int e = tid >> 3, g = tid & 7;
        int eg = e0 + e;
        int se = (eg < E_TOT) ? eg : 0;
        h8 r;
        if (g == 0) {
            const float* p = xb + (long)se * 8;
            float4 v0 = *(const float4*)p, v1 = *(const float4*)(p + 4);
            r[0] = (half_t)v0.x; r[1] = (half_t)v0.y; r[2] = (half_t)v0.z; r[3] = (half_t)v0.w;
            r[4] = (half_t)v1.x; r[5] = (half_t)v1.y; r[6] = (half_t)v1.z; r[7] = (half_t)v1.w;
        } else if (g <= 4) {
            int ia = (g == 1 || g == 3) ? 0 : 1;
            const float* pa = xb + (long)nidx[e][ia] * 8;
            const float* pb = xb + (long)nidx[e][ia + 2] * 8;
            float4 a0 = *(const float4*)pa, a1 = *(const float4*)(pa + 4);
            float4 b0 = *(const float4*)pb, b1 = *(const float4*)(pb + 4);
            float aa[8] = {a0.x, a0.y, a0.z, a0.w, a1.x, a1.y, a1.z, a1.w};
            float bb[8] = {b0.x, b0.y, b0.z, b0.w, b1.x, b1.y, b1.z, b1.w};
            if (g <= 2) {
#pragma unroll
                for (int j = 0; j < 8; ++j) r[j] = (half_t)(aa[j] + bb[j]);
            } else {
#pragma unroll
                for (int j = 0; j < 8; ++j) r[j] = (half_t)fabsf(aa[j] - bb[j]);
            }
        } else {
#pragma unroll
            for (int j = 0; j < 8; ++j) r[j] = (half_t)0.f;
        }
        Gl[(e * 8 + g) ^ (e & 7)] = r;
    }
    __syncthreads();

    f32x4 acc[4][2];
#pragma unroll
    for (int mt = 0; mt < 4; ++mt)
#pragma unroll
        for (int nt = 0; nt < 2; ++nt)
#pragma unroll
            for (int j = 0; j < 4; ++j) acc[mt][nt][j] = 0.f;

    const half_t* wt = war + (br ? OFF_W1P : OFF_W1E);
#pragma unroll
    for (int ks = 0; ks < 2; ++ks) {
        h8 bw[2];
#pragma unroll
        for (int nt = 0; nt < 2; ++nt)
            bw[nt] = *(const h8*)(wt + (long)(o0 + nt * 16 + l15) * 64 + ks * 32 + kg * 8);
#pragma unroll
        for (int mt = 0; mt < 4; ++mt) {
            int row = mt * 16 + l15;
            h8 a = Gl[row * 8 + ((ks * 4 + kg) ^ (row & 7))];
#pragma unroll
            for (int nt = 0; nt < 2; ++nt)
                acc[mt][nt] = __builtin_amdgcn_mfma_f32_16x16x32_f16(a, bw[nt], acc[mt][nt], 0, 0, 0);
        }
    }

    const float* bias = br ? bp1 : be1;
    half_t* yb = (br ? tmpp : tmpe) + (long)b * E_TOT * 128;
    float* part = br ? partp : parte;
    float bv[2], s1[2], s2[2];
#pragma unroll
    for (int nt = 0; nt < 2; ++nt) {
        bv[nt] = bias[o0 + nt * 16 + l15];
        s1[nt] = 0.f; s2[nt] = 0.f;
    }
#pragma unroll
    for (int mt = 0; mt < 4; ++mt) {
        int ebase = e0 + mt * 16 + (kg << 2);
#pragma unroll
        for (int j = 0; j < 4; ++j) {
            if (ebase + j < E_TOT) {
#pragma unroll
                for (int nt = 0; nt < 2; ++nt) {
                    float v = acc[mt][nt][j] + bv[nt];
                    yb[(long)(ebase + j) * 128 + o0 + nt * 16 + l15] = (half_t)v;
                    s1[nt] += v; s2[nt] += v * v;
                }
            }
        }
    }
#pragma unroll
    for (int nt = 0; nt < 2; ++nt) {
        s1[nt] += __shfl_xor(s1[nt], 16); s1[nt] += __shfl_xor(s1[nt], 32);
        s2[nt] += __shfl_xor(s2[nt], 16); s2[nt] += __shfl_xor(s2[nt], 32);
    }
    if (lane < 16) {
        long pb = ((long)b * NBLK + blockIdx.x) * 128;
#pragma unroll
        for (int nt = 0; nt < 2; ++nt) {
            part[(pb + o0 + nt * 16 + lane) * 2 + 0] = s1[nt];
            part[(pb + o0 + nt * 16 + lane) * 2 + 1] = s2[nt];
        }
    }
}

// ---------------------------------------------------------------------------
// layer-2 mesh conv, both branches via blockIdx.y. C=128 -> O=128, 8 waves.
// ---------------------------------------------------------------------------
__global__ __launch_bounds__(512)
void mesh2_both_k(const half_t* __restrict__ x1e, const half_t* __restrict__ x1p,
                  const int* __restrict__ gemm, const half_t* __restrict__ war,
                  const float* __restrict__ be, const float* __restrict__ bp,
                  half_t* __restrict__ tmpe, half_t* __restrict__ tmpp,
                  float* __restrict__ parte, float* __restrict__ partp)
{
    __shared__ h8 GlA[64 * 16];
    __shared__ h8 GlB[64 * 16];
    __shared__ int nidx[64][4];

    const int tid  = threadIdx.x;
    const int br   = blockIdx.y;
    const int b    = blockIdx.z;
    const int e0   = blockIdx.x * TILE_E;
    const int lane = tid & 63;
    const int wv   = tid >> 6;
    const int l15  = lane & 15;
    const int kg   = lane >> 4;
    const int o0   = wv * 16;

    const half_t* xb = (br ? x1p : x1e) + (long)b * E_TOT * 128;
    const half_t* wt = war + (br ? OFF_WTP2 : OFF_WTE2);

    if (tid < 256) {
        int e = tid >> 2, s = tid & 3;
        int eg = e0 + e;
        nidx[e][s] = (eg < E_TOT) ? gemm[((long)b * E_TOT + eg) * 4 + s] : 0;
    }

    auto stage_self = [&](h8* dst) {
#pragma unroll
        for (int t = 0; t < 2; ++t) {
            int q = t * 512 + tid;
            int e = q >> 4, c8 = q & 15;
            int eg = e0 + e;
            int se = (eg < E_TOT) ? eg : 0;
            dst[(e * 16 + c8) ^ (e & 7)] = *(const h8*)(xb + (long)se * 128 + c8 * 8);
        }
    };
    auto stage_pair = [&](h8* dstS, h8* dstD, int ia, int ib) {
#pragma unroll
        for (int t = 0; t < 2; ++t) {
            int q = t * 512 + tid;
            int e = q >> 4, c8 = q & 15;
            int na = nidx[e][ia], nb = nidx[e][ib];
            h8 a  = *(const h8*)(xb + (long)na * 128 + c8 * 8);
            h8 bq = *(const h8*)(xb + (long)nb * 128 + c8 * 8);
            int slot = (e * 16 + c8) ^ (e & 7);
            dstS[slot] = a + bq;
            dstD[slot] = habs8(a - bq);
        }
    };

    f32x4 acc[4];
#pragma unroll
    for (int mt = 0; mt < 4; ++mt)
#pragma unroll
        for (int j = 0; j < 4; ++j) acc[mt][j] = 0.f;

    auto compute_chunk = [&](const h8* buf, int s) {
#pragma unroll
        for (int ks = 0; ks < 4; ++ks) {
            h8 bw = *(const h8*)(wt + ((long)(o0 + l15) * 5 + s) * 128 + ks * 32 + kg * 8);
#pragma unroll
            for (int mt = 0; mt < 4; ++mt) {
                int row = mt * 16 + l15;
                h8 a = buf[row * 16 + ((ks * 4 + kg) ^ (row & 7))];
                acc[mt] = __builtin_amdgcn_mfma_f32_16x16x32_f16(a, bw, acc[mt], 0, 0, 0);
            }
        }
    };

    stage_self(GlA);
    __syncthreads();
    compute_chunk(GlA, 0);
    __syncthreads();
    stage_pair(GlA, GlB, 0, 2);
    __syncthreads();
    compute_chunk(GlA, 1);
    compute_chunk(GlB, 3);
    __syncthreads();
    stage_pair(GlA, GlB, 1, 3);
    __syncthreads();
    compute_chunk(GlA, 2);
    compute_chunk(GlB, 4);

    const float* bias = br ? bp : be;
    half_t* yb = (br ? tmpp : tmpe) + (long)b * E_TOT * 128;
    float* part = br ? partp : parte;
    float bv = bias[o0 + l15];
    float s1 = 0.f, s2 = 0.f;
#pragma unroll
    for (int mt = 0; mt < 4; ++mt) {
        int ebase = e0 + mt * 16 + (kg << 2);
#pragma unroll
        for (int j = 0; j < 4; ++j) {
            if (ebase + j < E_TOT) {
                float v = acc[mt][j] + bv;
                yb[(long)(ebase + j) * 128 + o0 + l15] = (half_t)v;
                s1 += v; s2 += v * v;
            }
        }
    }
    s1 += __shfl_xor(s1, 16); s1 += __shfl_xor(s1, 32);
    s2 += __shfl_xor(s2, 16); s2 += __shfl_xor(s2, 32);
    if (lane < 16) {
        long pb = ((long)b * NBLK + blockIdx.x) * 128;
        part[(pb + o0 + lane) * 2 + 0] = s1;
        part[(pb + o0 + lane) * 2 + 1] = s2;
    }
}

// ---------------------------------------------------------------------------
// decoder heads: combined linear+mesh conv, C=64 -> O=128 (o<64 linear via
// zero-padded weights), both heads via blockIdx.y. 8 waves.
// ---------------------------------------------------------------------------
__global__ __launch_bounds__(512)
void heads_k(const half_t* __restrict__ xall, const int* __restrict__ gemm,
             const half_t* __restrict__ war,
             const float* __restrict__ bal, const float* __restrict__ bbl,
             const float* __restrict__ bat, const float* __restrict__ bbt,
             half_t* __restrict__ xa2, half_t* __restrict__ xb2)
{
    __shared__ h8 GlA[64 * 8];
    __shared__ h8 GlB[64 * 8];
    __shared__ int nidx[64][4];

    const int tid  = threadIdx.x;
    const int br   = blockIdx.y;   // 0=A 1=B
    const int b    = blockIdx.z;
    const int e0   = blockIdx.x * TILE_E;
    const int lane = tid & 63;
    const int wv   = tid >> 6;
    const int l15  = lane & 15;
    const int kg   = lane >> 4;
    const int o0   = wv * 16;

    const half_t* xb = xall + (long)b * E_TOT * 64;
    const half_t* wt = war + (br ? OFF_WHB : OFF_WHA);

    if (tid < 256) {
        int e = tid >> 2, s = tid & 3;
        int eg = e0 + e;
        nidx[e][s] = (eg < E_TOT) ? gemm[((long)b * E_TOT + eg) * 4 + s] : 0;
    }

    auto stage_self = [&](h8* dst) {
        int q = tid;
        int e = q >> 3, c8 = q & 7;
        int eg = e0 + e;
        int se = (eg < E_TOT) ? eg : 0;
        dst[(e * 8 + c8) ^ (e & 7)] = *(const h8*)(xb + (long)se * 64 + c8 * 8);
    };
    auto stage_pair = [&](h8* dstS, h8* dstD, int ia, int ib) {
        int q = tid;
        int e = q >> 3, c8 = q & 7;
        int na = nidx[e][ia], nb = nidx[e][ib];
        h8 a  = *(const h8*)(xb + (long)na * 64 + c8 * 8);
        h8 bq = *(const h8*)(xb + (long)nb * 64 + c8 * 8);
        int slot = (e * 8 + c8) ^ (e & 7);
        dstS[slot] = a + bq;
        dstD[slot] = habs8(a - bq);
    };

    f32x4 acc[4];
#pragma unroll
    for (int mt = 0; mt < 4; ++mt)
#pragma unroll
        for (int j = 0; j < 4; ++j) acc[mt][j] = 0.f;

    auto compute_chunk = [&](const h8* buf, int s) {
#pragma unroll
        for (int ks = 0; ks < 2; ++ks) {
            h8 bw = *(const h8*)(wt + ((long)(o0 + l15) * 5 + s) * 64 + ks * 32 + kg * 8);
#pragma unroll
            for (int mt = 0; mt < 4; ++mt) {
                int row = mt * 16 + l15;
                h8 a = buf[row * 8 + ((ks * 4 + kg) ^ (row & 7))];
                acc[mt] = __builtin_amdgcn_mfma_f32_16x16x32_f16(a, bw, acc[mt], 0, 0, 0);
            }
        }
    };

    stage_self(GlA);
    __syncthreads();
    compute_chunk(GlA, 0);
    __syncthreads();
    stage_pair(GlA, GlB, 0, 2);
    __syncthreads();
    compute_chunk(GlA, 1);
    compute_chunk(GlB, 3);
    __syncthreads();
    stage_pair(GlA, GlB, 1, 3);
    __syncthreads();
    compute_chunk(GlA, 2);
    compute_chunk(GlB, 4);

    int o = o0 + l15;
    float bv = (o < 64) ? (br ? bbl[o] : bal[o]) : (br ? bbt[o - 64] : bat[o - 64]);
    half_t* yb = (br ? xb2 : xa2) + (long)b * E_TOT * 128;
#pragma unroll
    for (int mt = 0; mt < 4; ++mt) {
        int ebase = e0 + mt * 16 + (kg << 2);
#pragma unroll
        for (int j = 0; j < 4; ++j) {
            if (ebase + j < E_TOT)
                yb[(long)(ebase + j) * 128 + o] = (half_t)(acc[mt][j] + bv);
        }
    }
}

// ---------------------------------------------------------------------------
// gates: 1x1 conv C=128 -> O=128, both via blockIdx.y, 8 waves, stats.
// ---------------------------------------------------------------------------
__global__ __launch_bounds__(512)
void gates_k(const half_t* __restrict__ xa2, const half_t* __restrict__ xb2,
             const half_t* __restrict__ war,
             const float* __restrict__ baf, const float* __restrict__ bbf,
             half_t* __restrict__ tmpe, half_t* __restrict__ tmpp,
             float* __restrict__ parte, float* __restrict__ partp)
{
    __shared__ h8 Gl[64 * 16];

    const int tid  = threadIdx.x;
    const int br   = blockIdx.y;
    const int b    = blockIdx.z;
    const int e0   = blockIdx.x * TILE_E;
    const int lane = tid & 63;
    const int wv   = tid >> 6;
    const int l15  = lane & 15;
    const int kg   = lane >> 4;
    const int o0   = wv * 16;

    const half_t* xb = (br ? xb2 : xa2) + (long)b * E_TOT * 128;
    const half_t* wt = war + (br ? OFF_WTBF : OFF_WTAF);

#pragma unroll
    for (int t = 0; t < 2; ++t) {
        int q = t * 512 + tid;
        int e = q >> 4, c8 = q & 15;
        int eg = e0 + e;
        int se = (eg < E_TOT) ? eg : 0;
        Gl[(e * 16 + c8) ^ (e & 7)] = *(const h8*)(xb + (long)se * 128 + c8 * 8);
    }
    __syncthreads();

    f32x4 acc[4];
#pragma unroll
    for (int mt = 0; mt < 4; ++mt)
#pragma unroll
        for (int j = 0; j < 4; ++j) acc[mt][j] = 0.f;

#pragma unroll
    for (int ks = 0; ks < 4; ++ks) {
        h8 bw = *(const h8*)(wt + (long)(o0 + l15) * 128 + ks * 32 + kg * 8);
#pragma unroll
        for (int mt = 0; mt < 4; ++mt) {
            int row = mt * 16 + l15;
            h8 a = Gl[row * 16 + ((ks * 4 + kg) ^ (row & 7))];
            acc[mt] = __builtin_amdgcn_mfma_f32_16x16x32_f16(a, bw, acc[mt], 0, 0, 0);
        }
    }

    const float* bias = br ? bbf : baf;
    half_t* yb = (br ? tmpp : tmpe) + (long)b * E_TOT * 128;
    float* part = br ? partp : parte;
    float bv = bias[o0 + l15];
    float s1 = 0.f, s2 = 0.f;
#pragma unroll
    for (int mt = 0; mt < 4; ++mt) {
        int ebase = e0 + mt * 16 + (kg << 2);
#pragma unroll
        for (int j = 0; j < 4; ++j) {
            if (ebase + j < E_TOT) {
                float v = acc[mt][j] + bv;
                yb[(long)(ebase + j) * 128 + o0 + l15] = (half_t)v;
                s1 += v; s2 += v * v;
            }
        }
    }
    s1 += __shfl_xor(s1, 16); s1 += __shfl_xor(s1, 32);
    s2 += __shfl_xor(s2, 16); s2 += __shfl_xor(s2, 32);
    if (lane < 16) {
        long pb = ((long)b * NBLK + blockIdx.x) * 128;
        part[(pb + o0 + lane) * 2 + 0] = s1;
        part[(pb + o0 + lane) * 2 + 1] = s2;
    }
}

// ---------------------------------------------------------------------------
// x_all: 1x1 conv C=128 -> O=32, both halves via blockIdx.y. 4 waves split edges.
// ---------------------------------------------------------------------------
__global__ __launch_bounds__(256)
void xall_k(const half_t* __restrict__ x2e, const half_t* __restrict__ x2p,
            const half_t* __restrict__ war,
            const float* __restrict__ ba, const float* __restrict__ bb,
            half_t* __restrict__ xall)
{
    __shared__ h8 Gl[64 * 16];

    const int tid  = threadIdx.x;
    const int br   = blockIdx.y;
    const int b    = blockIdx.z;
    const int e0   = blockIdx.x * TILE_E;
    const int lane = tid & 63;
    const int wv   = tid >> 6;
    const int l15  = lane & 15;
    const int kg   = lane >> 4;
    const int eoff = wv * 16;

    const half_t* xb = (br ? x2p : x2e) + (long)b * E_TOT * 128;
    const half_t* wt = war + (br ? OFF_WTB : OFF_WTA);

#pragma unroll
    for (int t = 0; t < 4; ++t) {
        int q = t * 256 + tid;
        int e = q >> 4, c8 = q & 15;
        int eg = e0 + e;
        int se = (eg < E_TOT) ? eg : 0;
        Gl[(e * 16 + c8) ^ (e & 7)] = *(const h8*)(xb + (long)se * 128 + c8 * 8);
    }
    __syncthreads();

    f32x4 acc[2];
#pragma unroll
    for (int nt = 0; nt < 2; ++nt)
#pragma unroll
        for (int j = 0; j < 4; ++j) acc[nt][j] = 0.f;

#pragma unroll
    for (int ks = 0; ks < 4; ++ks) {
        h8 bw[2];
#pragma unroll
        for (int nt = 0; nt < 2; ++nt)
            bw[nt] = *(const h8*)(wt + (long)(nt * 16 + l15) * 128 + ks * 32 + kg * 8);
        int row = eoff + l15;
        h8 a = Gl[row * 16 + ((ks * 4 + kg) ^ (row & 7))];
#pragma unroll
        for (int nt = 0; nt < 2; ++nt)
            acc[nt] = __builtin_amdgcn_mfma_f32_16x16x32_f16(a, bw[nt], acc[nt], 0, 0, 0);
    }

    const float* bias = br ? bb : ba;
    half_t* yb = xall + (long)b * E_TOT * 64;
    int oOff = br * 32;
#pragma unroll
    for (int nt = 0; nt < 2; ++nt) {
        float bv = bias[nt * 16 + l15];
        int ebase = e0 + eoff + (kg << 2);
#pragma unroll
        for (int j = 0; j < 4; ++j) {
            if (ebase + j < E_TOT)
                yb[(long)(ebase + j) * 64 + oOff + nt * 16 + l15] = (half_t)(acc[nt][j] + bv);
        }
    }
}

// ---------------------------------------------------------------------------
// stats finalize, both branch buffers: grid 512 = (br, b, o)
// ---------------------------------------------------------------------------
__global__ __launch_bounds__(256)
void stats2_k(const float* __restrict__ parte, const float* __restrict__ partp,
              float* __restrict__ statse, float* __restrict__ statsp)
{
    int g = blockIdx.x;
    int br = g >> 8, rem = g & 255, b = rem >> 7, o = rem & 127;
    const float* part = br ? partp : parte;
    float* stats = br ? statsp : statse;
    int tid = threadIdx.x;
    float s1 = 0.f, s2 = 0.f;
    for (int k = tid; k < NBLK; k += 256) {
        long base = (((long)b * NBLK + k) * 128 + o) * 2;
        s1 += part[base];
        s2 += part[base + 1];
    }
#pragma unroll
    for (int d = 1; d < 64; d <<= 1) {
        s1 += __shfl_xor(s1, d);
        s2 += __shfl_xor(s2, d);
    }
    __shared__ float r1[4], r2[4];
    int wv = tid >> 6;
    if ((tid & 63) == 0) { r1[wv] = s1; r2[wv] = s2; }
    __syncthreads();
    if (tid == 0) {
        s1 = r1[0] + r1[1] + r1[2] + r1[3];
        s2 = r2[0] + r2[1] + r2[2] + r2[3];
        float mean = s1 / (float)E_TOT;
        float var  = s2 / (float)E_TOT - mean * mean;
        var = fmaxf(var, 0.f);
        stats[(b * 128 + o) * 2 + 0] = mean;
        stats[(b * 128 + o) * 2 + 1] = rsqrtf(var + 1e-5f);
    }
}

// ---------------------------------------------------------------------------
// x1 = relu(inorm(tmp)), both branches in one launch
// ---------------------------------------------------------------------------
__global__ __launch_bounds__(256)
void norm_act2_k(const half_t* __restrict__ tmpe, const half_t* __restrict__ tmpp,
                 const float* __restrict__ statse, const float* __restrict__ statsp,
                 half_t* __restrict__ x1e, half_t* __restrict__ x1p)
{
    const long PER = (long)B_TOT * E_TOT * 16;   // h8 units per branch
    long q = (long)blockIdx.x * 256 + threadIdx.x;
    if (q >= 2 * PER) return;
    int br = (q >= PER);
    q -= (long)br * PER;
    const half_t* src = br ? tmpp : tmpe;
    const float* stats = br ? statsp : statse;
    half_t* dst = br ? x1p : x1e;
    long idx = q * 8;
    int c = (int)(idx & 127);
    int b = (int)((idx >> 7) / E_TOT);
    h8 v = *(const h8*)&src[idx];
    h8 r;
#pragma unroll
    for (int j = 0; j < 8; ++j) {
        float2 st = *(const float2*)&stats[(b * 128 + c + j) * 2];
        float t = ((float)v[j] - st.x) * st.y;
        r[j] = (half_t)fmaxf(t, 0.f);
    }
    *(h8*)&dst[idx] = r;
}

// ---------------------------------------------------------------------------
// x2 = relu(inorm(tmp)+x1): f32 channel-major out section + f16 copy. Both
// branches: blockIdx.y = br*4 + cg.
// ---------------------------------------------------------------------------
__global__ __launch_bounds__(256)
void normres2_k(const half_t* __restrict__ tmpe, const half_t* __restrict__ tmpp,
                const half_t* __restrict__ x1e, const half_t* __restrict__ x1p,
                const float* __restrict__ statse, const float* __restrict__ statsp,
                float* __restrict__ outb,
                half_t* __restrict__ x2e, half_t* __restrict__ x2p)
{
    __shared__ float T[32 * 68];
    int br = blockIdx.y >> 2, cg = blockIdx.y & 3;
    int b = blockIdx.z;
    int e0 = blockIdx.x * 64;
    int tid = threadIdx.x;
    const half_t* xin = br ? tmpp : tmpe;
    const half_t* res = br ? x1p : x1e;
    const float* stats = br ? statsp : statse;
    half_t* x2b = br ? x2p : x2e;
    int sect = br * 128;
#pragma unroll
    for (int i = 0; i < 2; ++i) {
        int q = tid + i * 256;
        int e = q >> 3, cq = q & 7;
        int eg = e0 + e;
        int se = (eg < E_TOT) ? eg : (E_TOT - 1);
        int c = cg * 32 + cq * 4;
        long base = ((long)b * E_TOT + se) * 128 + c;
        h4 v4 = *(const h4*)&xin[base];
        h4 r4 = *(const h4*)&res[base];
        h4 o4;
#pragma unroll
        for (int j = 0; j < 4; ++j) {
            float2 st = *(const float2*)&stats[(b * 128 + c + j) * 2];
            float t = ((float)v4[j] - st.x) * st.y + (float)r4[j];
            t = fmaxf(t, 0.f);
            T[(cq * 4 + j) * 68 + e] = t;
            o4[j] = (half_t)t;
        }
        if (eg < E_TOT) *(h4*)&x2b[base] = o4;
    }
    __syncthreads();
#pragma unroll
    for (int i = 0; i < 2; ++i) {
        int q = tid + i * 256;
        int cl = q >> 4, eq = q & 15;
        int e4 = e0 + eq * 4;
        int cglob = sect + cg * 32 + cl;
        float4 v = *(const float4*)&T[cl * 68 + eq * 4];
        long obase = ((long)b * 384 + cglob) * E_TOT + e4;
        if (e4 + 3 < E_TOT) {
            *(float4*)&outb[obase] = v;
        } else {
            const float* vp = &v.x;
            for (int j = 0; j < 4; ++j)
                if (e4 + j < E_TOT) outb[obase + j] = vp[j];
        }
    }
}

// ---------------------------------------------------------------------------
// fused gates-norm + softmax2 + aggregate, reading f16 copies of x2e/x2p.
// ---------------------------------------------------------------------------
__global__ __launch_bounds__(256)
void gate_agg2_k(const half_t* __restrict__ tA, const half_t* __restrict__ tB,
                 const float* __restrict__ statsA, const float* __restrict__ statsB,
                 const half_t* __restrict__ x2e, const half_t* __restrict__ x2p,
                 float* __restrict__ outb)
{
    __shared__ float T[32 * 68];
    int b = blockIdx.z, cg = blockIdx.y;
    int e0 = blockIdx.x * 64;
    int tid = threadIdx.x;
#pragma unroll
    for (int i = 0; i < 2; ++i) {
        int q = tid + i * 256;
        int e = q >> 3, cq = q & 7;
        int eg = e0 + e;
        int se = (eg < E_TOT) ? eg : (E_TOT - 1);
        int c = cg * 32 + cq * 4;
        long base = ((long)b * E_TOT + se) * 128 + c;
        h4 a4 = *(const h4*)&tA[base];
        h4 b4 = *(const h4*)&tB[base];
        h4 xe4 = *(const h4*)&x2e[base];
        h4 xp4 = *(const h4*)&x2p[base];
#pragma unroll
        for (int j = 0; j < 4; ++j) {
            float2 sa = *(const float2*)&statsA[(b * 128 + c + j) * 2];
            float2 sb = *(const float2*)&statsB[(b * 128 + c + j) * 2];
            float na = sigmoidf_(((float)a4[j] - sa.x) * sa.y);
            float nb = sigmoidf_(((float)b4[j] - sb.x) * sb.y);
            float s = sigmoidf_(na - nb);
            T[(cq * 4 + j) * 68 + e] = (float)xe4[j] * s + (float)xp4[j] * (1.f - s);
        }
    }
    __syncthreads();
#pragma unroll
    for (int i = 0; i < 2; ++i) {
        int q = tid + i * 256;
        int cl = q >> 4, eq = q & 15;
        int e4 = e0 + eq * 4;
        int cglob = cg * 32 + cl;
        float4 v = *(const float4*)&T[cl * 68 + eq * 4];
        long ab = ((long)b * 384 + 256 + cglob) * E_TOT + e4;
        if (e4 + 3 < E_TOT) {
            *(float4*)&outb[ab] = v;
        } else {
            const float* vp = &v.x;
            for (int j = 0; j < 4; ++j)
                if (e4 + j < E_TOT) outb[ab + j] = vp[j];
        }
    }
}

// ---------------------------------------------------------------------------
extern "C" void kernel_launch(void* const* d_in, const int* in_sizes, int n_in,
                              void* d_out, int out_size, void* d_ws, size_t ws_size,
                              hipStream_t stream)
{
    const float* fe   = (const float*)d_in[0];
    const int*   gemm = (const int*)  d_in[1];
    const float* w_e1 = (const float*)d_in[2];  const float* b_e1 = (const float*)d_in[3];
    const float* w_p1 = (const float*)d_in[4];  const float* b_p1 = (const float*)d_in[5];
    const float* w_e2 = (const float*)d_in[6];  const float* b_e2 = (const float*)d_in[7];
    const float* w_p2 = (const float*)d_in[8];  const float* b_p2 = (const float*)d_in[9];
    const float* wa   = (const float*)d_in[10]; const float* ba   = (const float*)d_in[11];
    const float* wb   = (const float*)d_in[12]; const float* bb   = (const float*)d_in[13];
    const float* wal  = (const float*)d_in[14]; const float* bal  = (const float*)d_in[15];
    const float* wbl  = (const float*)d_in[16]; const float* bbl  = (const float*)d_in[17];
    const float* wat  = (const float*)d_in[18]; const float* bat  = (const float*)d_in[19];
    const float* wbt  = (const float*)d_in[20]; const float* bbt  = (const float*)d_in[21];
    const float* waf  = (const float*)d_in[22]; const float* baf  = (const float*)d_in[23];
    const float* wbf  = (const float*)d_in[24]; const float* bbf  = (const float*)d_in[25];
    float* out = (float*)d_out;

    const long EB = (long)E_TOT;

    char* wp = (char*)d_ws;
    auto alloc = [&](size_t bytes) -> void* {
        void* r = (void*)wp;
        wp += (bytes + 255) & ~(size_t)255;
        return r;
    };
    float*  FET    = (float*)alloc((size_t)B_TOT * EB * 8 * 4);
    half_t* TMP_E  = (half_t*)alloc((size_t)B_TOT * EB * 128 * 2);
    half_t* TMP_P  = (half_t*)alloc((size_t)B_TOT * EB * 128 * 2);
    half_t* X1E    = (half_t*)alloc((size_t)B_TOT * EB * 128 * 2);   // later XA2
    half_t* X1P    = (half_t*)alloc((size_t)B_TOT * EB * 128 * 2);   // later XB2
    half_t* X2E    = (half_t*)alloc((size_t)B_TOT * EB * 128 * 2);
    half_t* X2P    = (half_t*)alloc((size_t)B_TOT * EB * 128 * 2);
    half_t* XALL   = (half_t*)alloc((size_t)B_TOT * EB * 64 * 2);
    float*  PART_E = (float*)alloc((size_t)B_TOT * NBLK * 128 * 2 * 4);
    float*  PART_P = (float*)alloc((size_t)B_TOT * NBLK * 128 * 2 * 4);
    float*  STATSE = (float*)alloc((size_t)B_TOT * 128 * 2 * 4);
    float*  STATSP = (float*)alloc((size_t)B_TOT * 128 * 2 * 4);
    half_t* WAR    = (half_t*)alloc((size_t)WARENA_N * 2);

    if ((size_t)(wp - (char*)d_ws) > ws_size) {
        fprintf(stderr, "kernel_launch: ws too small (%zu < %zu)\n",
                ws_size, (size_t)(wp - (char*)d_ws));
        return;
    }

    half_t* XA2 = X1E;   // aliases: X1 dead after normres2
    half_t* XB2 = X1P;

    dim3 blk256(256), blk512(512);
    dim3 gE2(NBLK, 2, B_TOT);
    dim3 gE1(NBLK, B_TOT);
    dim3 gT((E_TOT + 255) / 256, 1, B_TOT);
    dim3 gN8(NBLK, 8, B_TOT);
    dim3 gN4(NBLK, 4, B_TOT);
    int gA2 = (int)((2 * (long)B_TOT * EB * 16 + 255) / 256);

    // 1-2: prep
    wprep_k<<<dim3(320, 10, 1), blk256, 0, stream>>>(WAR,
        w_e1, w_p1, w_e2, w_p2, wat, wbt, wa, wb, wal, wbl, waf, wbf);
    transpose_in_k<<<gT, blk256, 0, stream>>>(fe, FET);

    // 3-5: layer 1 (both branches)
    mesh1_both_k<<<gE1, blk512, 0, stream>>>(FET, gemm, WAR, b_e1, b_p1,
        TMP_E, TMP_P, PART_E, PART_P);
    stats2_k<<<512, blk256, 0, stream>>>(PART_E, PART_P, STATSE, STATSP);
    norm_act2_k<<<gA2, blk256, 0, stream>>>(TMP_E, TMP_P, STATSE, STATSP, X1E, X1P);

    // 6-8: layer 2 (both branches) + norm/res
    mesh2_both_k<<<gE2, blk512, 0, stream>>>(X1E, X1P, gemm, WAR, b_e2, b_p2,
        TMP_E, TMP_P, PART_E, PART_P);
    stats2_k<<<512, blk256, 0, stream>>>(PART_E, PART_P, STATSE, STATSP);
    normres2_k<<<gN8, blk256, 0, stream>>>(TMP_E, TMP_P, X1E, X1P, STATSE, STATSP,
        out, X2E, X2P);

    // 9: x_all
    xall_k<<<gE2, blk256, 0, stream>>>(X2E, X2P, WAR, ba, bb, XALL);

    // 10: decoder heads (linear+mesh fused, A and B)
    heads_k<<<gE2, blk512, 0, stream>>>(XALL, gemm, WAR, bal, bbl, bat, bbt, XA2, XB2);

    // 11-13: gates + aggregate
    gates_k<<<gE2, blk512, 0, stream>>>(XA2, XB2, WAR, baf, bbf,
        TMP_E, TMP_P, PART_E, PART_P);
    stats2_k<<<512, blk256, 0, stream>>>(PART_E, PART_P, STATSE, STATSP);
    gate_agg2_k<<<gN4, blk256, 0, stream>>>(TMP_E, TMP_P, STATSE, STATSP,
        X2E, X2P, out);
}